// Round 10
// baseline (419.654 us; speedup 1.0000x reference)
//
#include <hip/hip_runtime.h>
#include <math.h>

#define EPS 1e-5f
#define LOG2E 1.44269504088896340736f

#define AS_GLOBAL __attribute__((address_space(1)))
#define AS_LDS    __attribute__((address_space(3)))

// ---- shared affine-fold helper: A,B from sums (instance+batch norm + p1) ----
__device__ __forceinline__ float2 ab_from(float s1, float s2, float bs, float bs2,
    float hw, float Nf, float si_, float sb, float bnw_c, float bnb_c, float p1v) {
  float inv = 1.0f / hw;
  float mi = s1 * inv, vi = s2 * inv - mi * mi;
  float ri = rsqrtf(vi + EPS);
  float invb = 1.0f / (Nf * hw);
  float mb = bs * invb, vb = bs2 * invb - mb * mb;
  float rb = rsqrtf(vb + EPS);
  float A = 1.0f + si_ * ri + sb * rb * bnw_c;
  float B = -(si_ * ri * mi + sb * rb * bnw_c * mb) + sb * bnb_c;
  return make_float2(A * p1v, B * p1v);
}

// Partial-stats layout: P[c2][NT] planar, c2 = 2*c (+1 for sumsq), NT = producer grid.
__device__ __forceinline__ void compute_AB_P(
    const float* __restrict__ P, int n, int NT, int T, float hw, float Nf,
    const float* __restrict__ inp, const float* __restrict__ lnp,
    const float* __restrict__ bnp, const float* __restrict__ bnw,
    const float* __restrict__ bnb, const float* __restrict__ p1p,
    const float* __restrict__ p2p, float* pA, float* pB, float* pP2,
    float* sred /* __shared__ float[12] */) {
  int t = threadIdx.x;
  if (t == 0) *pP2 = p2p[0];
  if (t < 192) {
    int c2 = t >> 5, l = t & 31;
    const float* pp = P + c2 * NT;
    float aAll = 0.f, aOwn = 0.f;
    int base = n * T;
    #pragma unroll 4
    for (int i = l; i < NT; i += 32) {
      float v = pp[i];
      aAll += v;
      if ((unsigned)(i - base) < (unsigned)T) aOwn += v;
    }
    #pragma unroll
    for (int off = 16; off; off >>= 1) {
      aAll += __shfl_down(aAll, off, 32);
      aOwn += __shfl_down(aOwn, off, 32);
    }
    if (l == 0) { sred[c2] = aOwn; sred[6 + c2] = aAll; }
  }
  __syncthreads();
  if (t < 3) {
    int c = t;
    float si_ = inp[0] + inp[1] + inp[2] + lnp[0] + lnp[1] + lnp[2];
    float sb = bnp[0] + bnp[1] + bnp[2];
    float2 ab = ab_from(sred[2 * c], sred[2 * c + 1], sred[6 + 2 * c],
                        sred[6 + 2 * c + 1], hw, Nf, si_, sb, bnw[c], bnb[c],
                        p1p[0]);
    pA[c] = ab.x;
    pB[c] = ab.y;
  }
  __syncthreads();
}

// stats block-reduce (256 threads, all must participate): plain store, NO atomics.
#define STATS_REDUCE_STORE(scv, sqv, sumsp, bidv)                             \
  {                                                                           \
    _Pragma("unroll")                                                         \
    for (int off = 32; off; off >>= 1) {                                      \
      _Pragma("unroll")                                                       \
      for (int c = 0; c < 3; ++c) {                                           \
        scv[c] += __shfl_down(scv[c], off);                                   \
        sqv[c] += __shfl_down(sqv[c], off);                                   \
      }                                                                       \
    }                                                                         \
    __shared__ float redS[4][3], redQ[4][3];                                  \
    int wid = threadIdx.x >> 6, lane = threadIdx.x & 63;                      \
    if (lane == 0) {                                                          \
      _Pragma("unroll")                                                       \
      for (int c = 0; c < 3; ++c) { redS[wid][c] = scv[c]; redQ[wid][c] = sqv[c]; } \
    }                                                                         \
    __syncthreads();                                                          \
    if (threadIdx.x < 3) {                                                    \
      int c = threadIdx.x;                                                    \
      int NTg = (int)gridDim.x;                                               \
      sumsp[(2 * c) * NTg + (bidv)] =                                         \
          redS[0][c] + redS[1][c] + redS[2][c] + redS[3][c];                  \
      sumsp[(2 * c + 1) * NTg + (bidv)] =                                     \
          redQ[0][c] + redQ[1][c] + redQ[2][c] + redQ[3][c];                  \
    }                                                                         \
  }

// XCD-aware bijective swizzle (grid must be a multiple of 8).
__device__ __forceinline__ int xcd_swz() {
  return ((int)(blockIdx.x & 7)) * ((int)gridDim.x >> 3) + ((int)blockIdx.x >> 3);
}

// ---- staging value loader ----
// MODE: 0=direct, 1=fused affine float2 (+noise), 2=sum4 partials, 3=gather small grid
template <int MODE, bool IDENT>
__device__ __forceinline__ float stage_val(
    const float* __restrict__ inb, size_t ps,
    const float2* __restrict__ pyu, size_t pbase,
    int Hin, int gy, int gx, int Sp, int logrp,
    const float* pA, const float* pB, float pP2v,
    const float* __restrict__ pnoise, int cc) {
  if (MODE == 1) {
    int gxs = IDENT ? gx : ((gx * Sp) >> logrp);
    int rbase = IDENT ? gy * Sp : ((gy * Sp) >> logrp) * Sp;
    float2 v = pyu[pbase + (size_t)cc * Sp * Sp + rbase + gxs];
    float val = pA[cc] * v.x + pB[cc] + pP2v * v.y;
    if (pnoise) val += pnoise[((size_t)cc * Hin + gy) * Hin + gx];
    return val;
  } else if (MODE == 2) {
    size_t idx = ((size_t)cc * Hin + gy) * Hin + gx;
    return inb[idx] + inb[idx + ps] + inb[idx + 2 * ps] + inb[idx + 3 * ps];
  } else if (MODE == 3) {
    int gys = (gy * Sp) >> logrp, gxs = (gx * Sp) >> logrp;
    return inb[(cc * Sp + gys) * Sp + gxs];
  } else {
    return inb[((size_t)cc * Hin + gy) * Hin + gx];
  }
}

// ---- division-free 2D staging of a 3 x IHv x 68 tile ----
template <int MODE, bool IDENT, int IHv>
__device__ __forceinline__ void stage_tile(
    float* __restrict__ lin, const float* __restrict__ inb, size_t ps,
    const float2* __restrict__ pyu, size_t pbase,
    int Hin, int sy0, int sx0, int Sp, int logrp,
    const float* pA, const float* pB, float pP2v,
    const float* __restrict__ pnoise) {
  const int IW = 68;
  int colt = threadIdx.x & 63;
  int r4 = threadIdx.x >> 6;
  int gx = sx0 + colt; gx = gx < Hin ? gx : Hin - 1;
  #pragma unroll
  for (int cc = 0; cc < 3; ++cc) {
    #pragma unroll
    for (int rb = 0; rb < IHv / 4; ++rb) {
      int rr = r4 + (rb << 2);
      int gy = sy0 + rr; gy = gy < Hin ? gy : Hin - 1;
      lin[(cc * IHv + rr) * IW + colt] =
          stage_val<MODE, IDENT>(inb, ps, pyu, pbase, Hin, gy, gx, Sp, logrp,
                                 pA, pB, pP2v, pnoise, cc);
    }
  }
  for (int t = threadIdx.x; t < 3 * IHv * 4; t += 256) {
    int col2 = 64 + (t & 3);
    int rowlin = t >> 2;
    int cc = rowlin / IHv, rr = rowlin - cc * IHv;
    int gx2 = sx0 + col2; gx2 = gx2 < Hin ? gx2 : Hin - 1;
    int gy = sy0 + rr; gy = gy < Hin ? gy : Hin - 1;
    lin[(cc * IHv + rr) * IW + col2] =
        stage_val<MODE, IDENT>(inb, ps, pyu, pbase, Hin, gy, gx2, Sp, logrp,
                               pA, pB, pP2v, pnoise, cc);
  }
}

// ---- LDS-tiled upsample conv (S==hc): 64 x THv tile, TX=4, float2 out ----
template <int SMODE, int THv>
__global__ __launch_bounds__(256) void conv_up_t(
    const float* __restrict__ in, const float2* __restrict__ pyu,
    float2* __restrict__ yu,
    const float* __restrict__ w1, const float* __restrict__ b1,
    const float* __restrict__ w2, const float* __restrict__ b2,
    float* __restrict__ sums, int Hin, int S, int r, int tilesX, int tilesY,
    const float* __restrict__ psums,
    const float* __restrict__ pinp, const float* __restrict__ plnp,
    const float* __restrict__ pbnp, const float* __restrict__ pbnw,
    const float* __restrict__ pbnb, const float* __restrict__ pp1,
    const float* __restrict__ pp2, const float* __restrict__ pnoise,
    int pN, int Sp, int logrp, int pNT, int pT) {
  const int TW = 64, IW = 68, IH = THv + 4, NH = THv / 16;
  __shared__ float lin[3 * IH * IW];
  __shared__ float pA[3], pB[3], pP2v, sred[12];
  int bid = xcd_swz();
  int tpi = tilesX * tilesY;
  int n = bid / tpi;
  int trem = bid - n * tpi;
  int tyB = trem / tilesX, txB = trem - tyB * tilesX;
  int px0 = txB * TW, py0 = tyB * THv;
  const float* inb = in + (size_t)n * 3 * Hin * Hin;
  if (SMODE == 1) {
    compute_AB_P(psums, n, pNT, pT, (float)(Hin * Hin), (float)pN, pinp, plnp,
                 pbnp, pbnw, pbnb, pp1, pp2, pA, pB, &pP2v, sred);
    size_t pbase = (size_t)n * 3 * Sp * Sp;
    stage_tile<1, false, IH>(lin, nullptr, 0, pyu, pbase, Hin, py0, px0, Sp,
                             logrp, pA, pB, pP2v, pnoise);
  } else if (SMODE == 3) {
    const float* smallb = in + (size_t)n * 3 * Sp * Sp;
    stage_tile<3, false, IH>(lin, smallb, 0, nullptr, 0, Hin, py0, px0, Sp,
                             logrp, nullptr, nullptr, 0.f, nullptr);
  } else {
    if (px0 + IW <= Hin && py0 + IH <= Hin) {
      for (int t4 = threadIdx.x; t4 < 3 * IH * 17; t4 += 256) {
        int cc = t4 / (IH * 17);
        int rem = t4 - cc * (IH * 17);
        int rr = rem / 17, j = rem - rr * 17;
        const float* src = inb + ((size_t)cc * Hin + py0 + rr) * Hin + px0 + 4 * j;
        int base = t4 - (threadIdx.x & 63);  // wave-uniform float4 index
        __builtin_amdgcn_global_load_lds(
            (const AS_GLOBAL void*)src,
            (AS_LDS void*)(lin + 4 * base), 16, 0, 0);
      }
    } else {
      stage_tile<0, false, IH>(lin, inb, 0, nullptr, 0, Hin, py0, px0, 0, 0,
                               nullptr, nullptr, 0.f, nullptr);
    }
  }
  __syncthreads();
  int tx = threadIdx.x & 15, ty = threadIdx.x >> 4;
  int lx0 = tx * 4;
  float a1[NH][3][4], a2[NH][3][4];
  #pragma unroll
  for (int h = 0; h < NH; ++h) {
    #pragma unroll
    for (int c = 0; c < 3; ++c) {
      float bb1 = b1[c], bb2 = b2[c];
      #pragma unroll
      for (int x = 0; x < 4; ++x) { a1[h][c][x] = bb1; a2[h][c][x] = bb2; }
    }
  }
  #pragma unroll 1
  for (int ci = 0; ci < 3; ++ci) {
    const float* wp1 = w1 + ci * 25;
    const float* wp2 = w2 + ci * 25;
    #pragma unroll
    for (int h = 0; h < NH; ++h) {
      const float* lrow = lin + (ci * IH + ty + 16 * h) * IW + lx0;
      float v[5][8];
      #pragma unroll
      for (int ky = 0; ky < 5; ++ky) {
        #pragma unroll
        for (int j = 0; j < 8; ++j) { v[ky][j] = lrow[ky * IW + j]; }
      }
      #pragma unroll
      for (int ky = 0; ky < 5; ++ky) {
        #pragma unroll
        for (int c = 0; c < 3; ++c) {
          #pragma unroll
          for (int kx = 0; kx < 5; ++kx) {
            float wa = wp1[c * 75 + ky * 5 + kx];
            float wb = wp2[c * 75 + ky * 5 + kx];
            #pragma unroll
            for (int x = 0; x < 4; ++x) {
              a1[h][c][x] = fmaf(v[ky][kx + x], wa, a1[h][c][x]);
              a2[h][c][x] = fmaf(v[ky][kx + x], wb, a2[h][c][x]);
            }
          }
        }
      }
    }
  }
  float sc[3] = {0.f, 0.f, 0.f}, sq[3] = {0.f, 0.f, 0.f};
  int hc = S;
  int px = px0 + lx0;
  #pragma unroll
  for (int h = 0; h < NH; ++h) {
    int py = py0 + ty + 16 * h;
    bool valid = (py < S) && (px < S);
    if (valid) {
      float wy = (float)(((py + 1) * r + hc - 1) / hc - (py * r + hc - 1) / hc);
      float wx[4];
      #pragma unroll
      for (int x = 0; x < 4; ++x) {
        int pxx = px + x;
        wx[x] = (float)(((pxx + 1) * r + hc - 1) / hc - (pxx * r + hc - 1) / hc);
      }
      #pragma unroll
      for (int c = 0; c < 3; ++c) {
        size_t idx = ((size_t)(n * 3 + c) * S + py) * S + px;
        float2* yp = yu + idx;
        *reinterpret_cast<float4*>(yp) =
            make_float4(a1[h][c][0], a2[h][c][0], a1[h][c][1], a2[h][c][1]);
        *reinterpret_cast<float4*>(yp + 2) =
            make_float4(a1[h][c][2], a2[h][c][2], a1[h][c][3], a2[h][c][3]);
        #pragma unroll
        for (int x = 0; x < 4; ++x) {
          float wgt = wy * wx[x];
          sc[c] += a1[h][c][x] * wgt;
          sq[c] += a1[h][c][x] * a1[h][c][x] * wgt;
        }
      }
    }
  }
  STATS_REDUCE_STORE(sc, sq, sums, bid)
}

// ---- LDS-tiled downsample conv (ratio<2.05): 32 x 8 tile, float2 out ----
template <int SMODE, bool IDENT>
__global__ __launch_bounds__(256) void conv_dn_t(
    const float* __restrict__ in, const float2* __restrict__ pyu,
    float2* __restrict__ yu,
    const float* __restrict__ w1, const float* __restrict__ b1,
    const float* __restrict__ w2, const float* __restrict__ b2,
    float* __restrict__ sums, int Hin, int S, int hc, int logr,
    int tilesX, int tilesY,
    const float* __restrict__ psums,
    const float* __restrict__ pinp, const float* __restrict__ plnp,
    const float* __restrict__ pbnp, const float* __restrict__ pbnw,
    const float* __restrict__ pbnb, const float* __restrict__ pp1,
    const float* __restrict__ pp2, const float* __restrict__ pnoise,
    int pN, int Sp, int logrp, int pNT, int pT) {
  const int TW = 32, TH = 8, IW = 68, IH = 20;
  __shared__ float lin[3 * IH * IW];
  __shared__ float pA[3], pB[3], pP2v, sred[12];
  int bid = xcd_swz();
  int tpi = tilesX * tilesY;
  int n = bid / tpi;
  int trem = bid - n * tpi;
  int tyB = trem / tilesX, txB = trem - tyB * tilesX;
  int px0 = txB * TW, py0 = tyB * TH;
  int sy0 = (py0 * hc) >> logr, sx0 = (px0 * hc) >> logr;
  const float* inb = in + (size_t)n * 3 * Hin * Hin;
  if (SMODE == 1) {
    compute_AB_P(psums, n, pNT, pT, (float)(Hin * Hin), (float)pN, pinp, plnp,
                 pbnp, pbnw, pbnb, pp1, pp2, pA, pB, &pP2v, sred);
    size_t pbase = (size_t)n * 3 * Sp * Sp;
    stage_tile<1, IDENT, IH>(lin, nullptr, 0, pyu, pbase, Hin, sy0, sx0, Sp,
                             logrp, pA, pB, pP2v, pnoise);
  } else if (SMODE == 2) {
    size_t ps = (size_t)96 * Hin * Hin;
    stage_tile<2, false, IH>(lin, inb, ps, nullptr, 0, Hin, sy0, sx0, 0, 0,
                             nullptr, nullptr, 0.f, nullptr);
  } else {
    stage_tile<0, false, IH>(lin, inb, 0, nullptr, 0, Hin, sy0, sx0, 0, 0,
                             nullptr, nullptr, 0.f, nullptr);
  }
  __syncthreads();
  int tx = threadIdx.x & 31, ty = threadIdx.x >> 5;
  int px = px0 + tx, py = py0 + ty;
  int sxl = ((px * hc) >> logr) - sx0;
  int syl = ((py * hc) >> logr) - sy0;
  float a1[3], a2[3];
  #pragma unroll
  for (int c = 0; c < 3; ++c) { a1[c] = b1[c]; a2[c] = b2[c]; }
  #pragma unroll
  for (int ci = 0; ci < 3; ++ci) {
    const float* lrow = lin + (ci * IH + syl) * IW + sxl;
    const float* wp1 = w1 + ci * 25;
    const float* wp2 = w2 + ci * 25;
    #pragma unroll
    for (int ky = 0; ky < 5; ++ky) {
      float v[5];
      #pragma unroll
      for (int j = 0; j < 5; ++j) { v[j] = lrow[ky * IW + j]; }
      #pragma unroll
      for (int c = 0; c < 3; ++c) {
        #pragma unroll
        for (int kx = 0; kx < 5; ++kx) {
          a1[c] = fmaf(v[kx], wp1[c * 75 + ky * 5 + kx], a1[c]);
          a2[c] = fmaf(v[kx], wp2[c * 75 + ky * 5 + kx], a2[c]);
        }
      }
    }
  }
  float sc[3] = {0.f, 0.f, 0.f}, sq[3] = {0.f, 0.f, 0.f};
  bool valid = (py < S) && (px < S);
  if (valid) {
    #pragma unroll
    for (int c = 0; c < 3; ++c) {
      size_t idx = ((size_t)(n * 3 + c) * S + py) * S + px;
      yu[idx] = make_float2(a1[c], a2[c]);
      sc[c] += a1[c];
      sq[c] += a1[c] * a1[c];
    }
  }
  STATS_REDUCE_STORE(sc, sq, sums, bid)
}

// ---- Linear 512->768: one wave per output row, coalesced float4 ----
__global__ __launch_bounds__(256) void linear_wave(
    const float* __restrict__ z, const float* __restrict__ w,
    const float* __restrict__ b, float* __restrict__ out) {
  int row = (blockIdx.x << 2) + (threadIdx.x >> 6);
  int lane = threadIdx.x & 63;
  const float4* wr = reinterpret_cast<const float4*>(w + (size_t)row * 512);
  const float4* zz = reinterpret_cast<const float4*>(z);
  float acc = 0.f;
  #pragma unroll
  for (int i = 0; i < 2; ++i) {
    float4 wv = wr[lane + 64 * i];
    float4 zv = zz[lane + 64 * i];
    acc += wv.x * zv.x + wv.y * zv.y + wv.z * zv.z + wv.w * zv.w;
  }
  #pragma unroll
  for (int off = 32; off; off >>= 1) acc += __shfl_down(acc, off);
  if (lane == 0) out[row] = acc + b[row];
}

// ---- noise conv path (blocks 0,1) in one block, L0 from global ----
__global__ __launch_bounds__(256) void noise_rest(
    const float* __restrict__ L0g,
    const float* __restrict__ cw, const float* __restrict__ cb,
    const float* __restrict__ c2w, const float* __restrict__ c2b,
    const float* __restrict__ inp, const float* __restrict__ lnp,
    const float* __restrict__ bnp, const float* __restrict__ bnw,
    const float* __restrict__ bnb, const float* __restrict__ p1p,
    const float* __restrict__ p2p, float* __restrict__ nb0) {
  __shared__ float L0[768];
  __shared__ float ys0[432], u20[432];
  __shared__ float buf1[3072];
  __shared__ float ys1[2352], u21[2352];
  __shared__ float redS[4][3], redQ[4][3];
  __shared__ float AB[6];
  int tid = threadIdx.x;
  for (int t = tid; t < 768; t += 256) { L0[t] = L0g[t]; }
  __syncthreads();
  // ---- conv0: (3,16,16) -> S=12, r=32 ----
  {
    float sc[3] = {0, 0, 0}, sq[3] = {0, 0, 0};
    for (int p = tid; p < 144; p += 256) {
      int py = p / 12, px = p - py * 12;
      float a1[3], a2[3];
      #pragma unroll
      for (int c = 0; c < 3; ++c) { a1[c] = cb[c]; a2[c] = c2b[c]; }
      for (int ci = 0; ci < 3; ++ci) {
        #pragma unroll
        for (int ky = 0; ky < 5; ++ky) {
          const float* row = &L0[ci * 256 + (py + ky) * 16 + px];
          #pragma unroll
          for (int c = 0; c < 3; ++c) {
            #pragma unroll
            for (int kx = 0; kx < 5; ++kx) {
              a1[c] = fmaf(row[kx], cw[c * 75 + ci * 25 + ky * 5 + kx], a1[c]);
              a2[c] = fmaf(row[kx], c2w[c * 75 + ci * 25 + ky * 5 + kx], a2[c]);
            }
          }
        }
      }
      int wy = ((py + 1) * 32 + 11) / 12 - (py * 32 + 11) / 12;
      int wx = ((px + 1) * 32 + 11) / 12 - (px * 32 + 11) / 12;
      float wgt = (float)(wy * wx);
      #pragma unroll
      for (int c = 0; c < 3; ++c) {
        ys0[c * 144 + p] = a1[c];
        u20[c * 144 + p] = a2[c];
        sc[c] += a1[c] * wgt;
        sq[c] += a1[c] * a1[c] * wgt;
      }
    }
    #pragma unroll
    for (int off = 32; off; off >>= 1) {
      #pragma unroll
      for (int c = 0; c < 3; ++c) {
        sc[c] += __shfl_down(sc[c], off);
        sq[c] += __shfl_down(sq[c], off);
      }
    }
    int wid = tid >> 6, lane = tid & 63;
    if (lane == 0) {
      #pragma unroll
      for (int c = 0; c < 3; ++c) { redS[wid][c] = sc[c]; redQ[wid][c] = sq[c]; }
    }
    __syncthreads();
    if (tid < 3) {
      int c = tid;
      float s1 = redS[0][c] + redS[1][c] + redS[2][c] + redS[3][c];
      float s2 = redQ[0][c] + redQ[1][c] + redQ[2][c] + redQ[3][c];
      float si_ = inp[0] + inp[1] + inp[2] + lnp[0] + lnp[1] + lnp[2];
      float sb = bnp[0] + bnp[1] + bnp[2];
      float2 ab = ab_from(s1, s2, s1, s2, 1024.f, 1.f, si_, sb, bnw[c], bnb[c], p1p[0]);
      AB[c] = ab.x; AB[3 + c] = ab.y;
    }
    __syncthreads();
  }
  {
    float P2a = p2p[0];
    for (int t = tid; t < 3072; t += 256) {
      int c = t >> 10, p = t & 1023;
      int oy = p >> 5, ox = p & 31;
      int si = ((oy * 12) >> 5) * 12 + ((ox * 12) >> 5);
      buf1[t] = AB[c] * ys0[c * 144 + si] + AB[3 + c] + P2a * u20[c * 144 + si];
    }
  }
  __syncthreads();
  // ---- conv1: (3,32,32) -> S=28, r=64 ----
  {
    const float* w1 = cw + 225;
    const float* w2 = c2w + 225;
    float sc[3] = {0, 0, 0}, sq[3] = {0, 0, 0};
    for (int p = tid; p < 784; p += 256) {
      int py = p / 28, px = p - py * 28;
      float a1[3], a2[3];
      #pragma unroll
      for (int c = 0; c < 3; ++c) { a1[c] = cb[3 + c]; a2[c] = c2b[3 + c]; }
      for (int ci = 0; ci < 3; ++ci) {
        #pragma unroll
        for (int ky = 0; ky < 5; ++ky) {
          const float* row = &buf1[ci * 1024 + (py + ky) * 32 + px];
          #pragma unroll
          for (int c = 0; c < 3; ++c) {
            #pragma unroll
            for (int kx = 0; kx < 5; ++kx) {
              a1[c] = fmaf(row[kx], w1[c * 75 + ci * 25 + ky * 5 + kx], a1[c]);
              a2[c] = fmaf(row[kx], w2[c * 75 + ci * 25 + ky * 5 + kx], a2[c]);
            }
          }
        }
      }
      int wy = ((py + 1) * 64 + 27) / 28 - (py * 64 + 27) / 28;
      int wx = ((px + 1) * 64 + 27) / 28 - (px * 64 + 27) / 28;
      float wgt = (float)(wy * wx);
      #pragma unroll
      for (int c = 0; c < 3; ++c) {
        ys1[c * 784 + p] = a1[c];
        u21[c * 784 + p] = a2[c];
        sc[c] += a1[c] * wgt;
        sq[c] += a1[c] * a1[c] * wgt;
      }
    }
    #pragma unroll
    for (int off = 32; off; off >>= 1) {
      #pragma unroll
      for (int c = 0; c < 3; ++c) {
        sc[c] += __shfl_down(sc[c], off);
        sq[c] += __shfl_down(sq[c], off);
      }
    }
    int wid = tid >> 6, lane = tid & 63;
    __syncthreads();  // protect redS reuse
    if (lane == 0) {
      #pragma unroll
      for (int c = 0; c < 3; ++c) { redS[wid][c] = sc[c]; redQ[wid][c] = sq[c]; }
    }
    __syncthreads();
    if (tid < 3) {
      int c = tid;
      float s1 = redS[0][c] + redS[1][c] + redS[2][c] + redS[3][c];
      float s2 = redQ[0][c] + redQ[1][c] + redQ[2][c] + redQ[3][c];
      float si_ = inp[3] + inp[4] + inp[5] + lnp[3] + lnp[4] + lnp[5];
      float sb = bnp[3] + bnp[4] + bnp[5];
      float2 ab = ab_from(s1, s2, s1, s2, 4096.f, 1.f, si_, sb, bnw[3 + c], bnb[3 + c], p1p[1]);
      AB[c] = ab.x; AB[3 + c] = ab.y;
    }
    __syncthreads();
  }
  {
    float P2b = p2p[1];
    for (int t = tid; t < 12288; t += 256) {
      int c = t >> 12, p = t & 4095;
      int oy = p >> 6, ox = p & 63;
      int si = ((oy * 28) >> 6) * 28 + ((ox * 28) >> 6);
      nb0[t] = AB[c] * ys1[c * 784 + si] + AB[3 + c] + P2b * u21[c * 784 + si];
    }
  }
}

// ---- attention HW=1024, pass 1 (fused y2+QKV recompute) ----
__global__ __launch_bounds__(256) void attn_rows_f(
    const float2* __restrict__ yu, const float* __restrict__ sums,
    const float* __restrict__ inp, const float* __restrict__ lnp,
    const float* __restrict__ bnp, const float* __restrict__ bnw,
    const float* __restrict__ bnb, const float* __restrict__ p1p,
    const float* __restrict__ p2p,
    const float* __restrict__ qw, const float* __restrict__ qb,
    const float* __restrict__ kw, const float* __restrict__ kb,
    float* __restrict__ Mp, float* __restrict__ Lp, int S,
    int pNT, int pT) {
  __shared__ float pA[3], pB[3], pP2v, sred[12];
  __shared__ __align__(16) float y2s[768], qs[768];
  int bid = blockIdx.x;
  int np = bid & 3; bid >>= 2;
  int mc = bid & 3;
  int b = bid >> 2;
  compute_AB_P(sums, b, pNT, pT, 1024.f, 32.f, inp, lnp, bnp, bnw, bnb, p1p,
               p2p, pA, pB, &pP2v, sred);
  size_t ybase = (size_t)b * 3 * S * S;
  for (int t = threadIdx.x; t < 768; t += 256) {
    int c = t >> 8, j = t & 255;
    int n = (np << 8) + j;
    int oy = n >> 5, ox = n & 31;
    int si = ((oy * S) >> 5) * S + ((ox * S) >> 5);
    float2 v = yu[ybase + c * S * S + si];
    y2s[t] = pA[c] * v.x + pB[c] + pP2v * v.y;
  }
  __syncthreads();
  for (int t = threadIdx.x; t < 768; t += 256) {
    int o = t >> 8, j = t & 255;
    qs[t] = qb[o] + qw[o * 3] * y2s[j] + qw[o * 3 + 1] * y2s[256 + j] +
            qw[o * 3 + 2] * y2s[512 + j];
  }
  __syncthreads();
  int m = (mc << 8) + threadIdx.x;
  int oy = m >> 5, ox = m & 31;
  int si = ((oy * S) >> 5) * S + ((ox * S) >> 5);
  float ym[3];
  #pragma unroll
  for (int c = 0; c < 3; ++c) {
    float2 v = yu[ybase + c * S * S + si];
    ym[c] = pA[c] * v.x + pB[c] + pP2v * v.y;
  }
  float k0 = (kb[0] + kw[0] * ym[0] + kw[1] * ym[1] + kw[2] * ym[2]) * LOG2E;
  float k1 = (kb[1] + kw[3] * ym[0] + kw[4] * ym[1] + kw[5] * ym[2]) * LOG2E;
  float k2 = (kb[2] + kw[6] * ym[0] + kw[7] * ym[1] + kw[8] * ym[2]) * LOG2E;
  const float4* qa4 = reinterpret_cast<const float4*>(qs);
  const float4* qb4 = reinterpret_cast<const float4*>(qs + 256);
  const float4* qc4 = reinterpret_cast<const float4*>(qs + 512);
  float mr = -1e30f;
  #pragma unroll 4
  for (int j = 0; j < 64; ++j) {
    float4 qa = qa4[j], qbv = qb4[j], qc = qc4[j];
    float s0 = k0 * qa.x + k1 * qbv.x + k2 * qc.x;
    float s1 = k0 * qa.y + k1 * qbv.y + k2 * qc.y;
    float s2 = k0 * qa.z + k1 * qbv.z + k2 * qc.z;
    float s3 = k0 * qa.w + k1 * qbv.w + k2 * qc.w;
    mr = fmaxf(mr, fmaxf(fmaxf(s0, s1), fmaxf(s2, s3)));
  }
  float l = 0.f;
  #pragma unroll 4
  for (int j = 0; j < 64; ++j) {
    float4 qa = qa4[j], qbv = qb4[j], qc = qc4[j];
    float s0 = k0 * qa.x + k1 * qbv.x + k2 * qc.x;
    float s1 = k0 * qa.y + k1 * qbv.y + k2 * qc.y;
    float s2 = k0 * qa.z + k1 * qbv.z + k2 * qc.z;
    float s3 = k0 * qa.w + k1 * qbv.w + k2 * qc.w;
    l += exp2f(s0 - mr) + exp2f(s1 - mr) + exp2f(s2 - mr) + exp2f(s3 - mr);
  }
  int idx = (b * 4 + np) * 1024 + m;
  Mp[idx] = mr;
  Lp[idx] = l;
}

// ---- attention HW=1024, pass 2: partial buffers, NO atomics ----
__global__ __launch_bounds__(256) void attn_out_f(
    const float2* __restrict__ yu, const float* __restrict__ sums,
    const float* __restrict__ inp, const float* __restrict__ lnp,
    const float* __restrict__ bnp, const float* __restrict__ bnw,
    const float* __restrict__ bnb, const float* __restrict__ p1p,
    const float* __restrict__ p2p,
    const float* __restrict__ qw, const float* __restrict__ qb,
    const float* __restrict__ kw, const float* __restrict__ kb,
    const float* __restrict__ vw, const float* __restrict__ vb,
    const float* __restrict__ Mp, const float* __restrict__ Lp,
    float* __restrict__ aout, int S, int pNT, int pT) {
  __shared__ float pA[3], pB[3], pP2v, sred[12];
  __shared__ __align__(16) float ym[768], ks[768], vs[768], Ms[256], Ls[256];
  int bid = blockIdx.x;
  int mp = bid & 3; bid >>= 2;
  int nc = bid & 3;
  int b = bid >> 2;
  compute_AB_P(sums, b, pNT, pT, 1024.f, 32.f, inp, lnp, bnp, bnw, bnb, p1p,
               p2p, pA, pB, &pP2v, sred);
  size_t ybase = (size_t)b * 3 * S * S;
  for (int t = threadIdx.x; t < 768; t += 256) {
    int c = t >> 8, j = t & 255;
    int m = (mp << 8) + j;
    int oy = m >> 5, ox = m & 31;
    int si = ((oy * S) >> 5) * S + ((ox * S) >> 5);
    float2 v = yu[ybase + c * S * S + si];
    ym[t] = pA[c] * v.x + pB[c] + pP2v * v.y;
  }
  __syncthreads();
  for (int t = threadIdx.x; t < 768; t += 256) {
    int o = t >> 8, j = t & 255;
    float y0 = ym[j], y1 = ym[256 + j], y2v = ym[512 + j];
    ks[t] = (kb[o] + kw[o * 3] * y0 + kw[o * 3 + 1] * y1 + kw[o * 3 + 2] * y2v) * LOG2E;
    vs[t] = vb[o] + vw[o * 3] * y0 + vw[o * 3 + 1] * y1 + vw[o * 3 + 2] * y2v;
  }
  {
    int t = threadIdx.x;
    int m = (mp << 8) + t;
    float M0 = Mp[(b * 4 + 0) * 1024 + m], M1 = Mp[(b * 4 + 1) * 1024 + m];
    float M2 = Mp[(b * 4 + 2) * 1024 + m], M3 = Mp[(b * 4 + 3) * 1024 + m];
    float L0 = Lp[(b * 4 + 0) * 1024 + m], L1 = Lp[(b * 4 + 1) * 1024 + m];
    float L2 = Lp[(b * 4 + 2) * 1024 + m], L3 = Lp[(b * 4 + 3) * 1024 + m];
    float MM = fmaxf(fmaxf(M0, M1), fmaxf(M2, M3));
    float LL = L0 * exp2f(M0 - MM) + L1 * exp2f(M1 - MM) +
               L2 * exp2f(M2 - MM) + L3 * exp2f(M3 - MM);
    Ms[t] = MM;
    Ls[t] = 1.0f / LL;
  }
  __syncthreads();
  int n = (nc << 8) + threadIdx.x;
  int oy = n >> 5, ox = n & 31;
  int si = ((oy * S) >> 5) * S + ((ox * S) >> 5);
  float yn[3];
  #pragma unroll
  for (int c = 0; c < 3; ++c) {
    float2 v = yu[ybase + c * S * S + si];
    yn[c] = pA[c] * v.x + pB[c] + pP2v * v.y;
  }
  float q0 = qb[0] + qw[0] * yn[0] + qw[1] * yn[1] + qw[2] * yn[2];
  float q1 = qb[1] + qw[3] * yn[0] + qw[4] * yn[1] + qw[5] * yn[2];
  float q2 = qb[2] + qw[6] * yn[0] + qw[7] * yn[1] + qw[8] * yn[2];
  float a0 = 0.f, a1 = 0.f, a2 = 0.f;
  const float4* ka4 = reinterpret_cast<const float4*>(ks);
  const float4* kb4 = reinterpret_cast<const float4*>(ks + 256);
  const float4* kc4 = reinterpret_cast<const float4*>(ks + 512);
  const float4* va4 = reinterpret_cast<const float4*>(vs);
  const float4* vb4 = reinterpret_cast<const float4*>(vs + 256);
  const float4* vc4 = reinterpret_cast<const float4*>(vs + 512);
  const float4* mm4 = reinterpret_cast<const float4*>(Ms);
  const float4* ll4 = reinterpret_cast<const float4*>(Ls);
  #pragma unroll 2
  for (int j = 0; j < 64; ++j) {
    float4 ka = ka4[j], kbv = kb4[j], kc = kc4[j];
    float4 va = va4[j], vbv = vb4[j], vc = vc4[j];
    float4 mm = mm4[j], ll = ll4[j];
    float s, w;
    s = ka.x * q0 + kbv.x * q1 + kc.x * q2;
    w = exp2f(s - mm.x) * ll.x;
    a0 = fmaf(va.x, w, a0); a1 = fmaf(vbv.x, w, a1); a2 = fmaf(vc.x, w, a2);
    s = ka.y * q0 + kbv.y * q1 + kc.y * q2;
    w = exp2f(s - mm.y) * ll.y;
    a0 = fmaf(va.y, w, a0); a1 = fmaf(vbv.y, w, a1); a2 = fmaf(vc.y, w, a2);
    s = ka.z * q0 + kbv.z * q1 + kc.z * q2;
    w = exp2f(s - mm.z) * ll.z;
    a0 = fmaf(va.z, w, a0); a1 = fmaf(vbv.z, w, a1); a2 = fmaf(vc.z, w, a2);
    s = ka.w * q0 + kbv.w * q1 + kc.w * q2;
    w = exp2f(s - mm.w) * ll.w;
    a0 = fmaf(va.w, w, a0); a1 = fmaf(vbv.w, w, a1); a2 = fmaf(vc.w, w, a2);
  }
  if (mp == 0) { a0 += yn[0]; a1 += yn[1]; a2 += yn[2]; }
  size_t o0 = (size_t)mp * 98304 + (size_t)b * 3072 + n;
  aout[o0] = a0;
  aout[o0 + 1024] = a1;
  aout[o0 + 2048] = a2;
}

// ---- attention HW=256 + following conv, 1024 threads, 4-way split loops ----
__global__ __launch_bounds__(1024) void attn256_conv(
    const float2* __restrict__ yu, const float* __restrict__ sums,
    const float* __restrict__ inp, const float* __restrict__ lnp,
    const float* __restrict__ bnp, const float* __restrict__ bnw,
    const float* __restrict__ bnb, const float* __restrict__ p1p,
    const float* __restrict__ p2p,
    const float* __restrict__ qw, const float* __restrict__ qb,
    const float* __restrict__ kw, const float* __restrict__ kb,
    const float* __restrict__ vw, const float* __restrict__ vb,
    const float* __restrict__ cw1, const float* __restrict__ cb1,
    const float* __restrict__ cw2, const float* __restrict__ cb2,
    float2* __restrict__ yu_out, float* __restrict__ sums_out, int S, int r,
    int pNT, int pT) {
  __shared__ float pA[3], pB[3], pP2v, sred[12];
  __shared__ __align__(16) float y2s[768], qs[768], ks[768], vs[768];
  __shared__ __align__(16) float Ms[256], Ls[256];
  __shared__ float Mq[1024], Lq[1024];
  __shared__ float Oq[3072];
  __shared__ float redS[16][3], redQ[16][3];
  int tid = threadIdx.x;
  int quarter = tid >> 8;
  int lane256 = tid & 255;
  int b = blockIdx.x;
  compute_AB_P(sums, b, pNT, pT, 256.f, 32.f, inp, lnp, bnp, bnw, bnb, p1p,
               p2p, pA, pB, &pP2v, sred);
  size_t ybase = (size_t)b * 3 * S * S;
  if (tid < 768) {
    int c = tid >> 8, p = tid & 255;
    int oy = p >> 4, ox = p & 15;
    int si = ((oy * S) >> 4) * S + ((ox * S) >> 4);
    float2 v = yu[ybase + c * S * S + si];
    y2s[tid] = pA[c] * v.x + pB[c] + pP2v * v.y;
  }
  __syncthreads();
  if (tid < 768) {
    int o = tid >> 8, p = tid & 255;
    float y0 = y2s[p], y1 = y2s[256 + p], y2v = y2s[512 + p];
    qs[tid] = qb[o] + qw[o * 3] * y0 + qw[o * 3 + 1] * y1 + qw[o * 3 + 2] * y2v;
    ks[tid] = (kb[o] + kw[o * 3] * y0 + kw[o * 3 + 1] * y1 + kw[o * 3 + 2] * y2v) * LOG2E;
    vs[tid] = vb[o] + vw[o * 3] * y0 + vw[o * 3 + 1] * y1 + vw[o * 3 + 2] * y2v;
  }
  __syncthreads();
  {
    int m = lane256;
    float kx = ks[m], ky = ks[256 + m], kz = ks[512 + m];
    int n0 = quarter << 6;
    const float4* qa4 = reinterpret_cast<const float4*>(qs + n0);
    const float4* qb4 = reinterpret_cast<const float4*>(qs + 256 + n0);
    const float4* qc4 = reinterpret_cast<const float4*>(qs + 512 + n0);
    float mr = -1e30f;
    #pragma unroll 4
    for (int j = 0; j < 16; ++j) {
      float4 qa = qa4[j], qbv = qb4[j], qc = qc4[j];
      float s0 = kx * qa.x + ky * qbv.x + kz * qc.x;
      float s1 = kx * qa.y + ky * qbv.y + kz * qc.y;
      float s2 = kx * qa.z + ky * qbv.z + kz * qc.z;
      float s3 = kx * qa.w + ky * qbv.w + kz * qc.w;
      mr = fmaxf(mr, fmaxf(fmaxf(s0, s1), fmaxf(s2, s3)));
    }
    float l = 0.f;
    #pragma unroll 4
    for (int j = 0; j < 16; ++j) {
      float4 qa = qa4[j], qbv = qb4[j], qc = qc4[j];
      float s0 = kx * qa.x + ky * qbv.x + kz * qc.x;
      float s1 = kx * qa.y + ky * qbv.y + kz * qc.y;
      float s2 = kx * qa.z + ky * qbv.z + kz * qc.z;
      float s3 = kx * qa.w + ky * qbv.w + kz * qc.w;
      l += exp2f(s0 - mr) + exp2f(s1 - mr) + exp2f(s2 - mr) + exp2f(s3 - mr);
    }
    Mq[tid] = mr;
    Lq[tid] = l;
  }
  __syncthreads();
  if (tid < 256) {
    float M0 = Mq[tid], M1 = Mq[256 + tid], M2 = Mq[512 + tid], M3 = Mq[768 + tid];
    float L0 = Lq[tid], L1 = Lq[256 + tid], L2 = Lq[512 + tid], L3 = Lq[768 + tid];
    float MM = fmaxf(fmaxf(M0, M1), fmaxf(M2, M3));
    float LL = L0 * exp2f(M0 - MM) + L1 * exp2f(M1 - MM) +
               L2 * exp2f(M2 - MM) + L3 * exp2f(M3 - MM);
    Ms[tid] = MM;
    Ls[tid] = 1.0f / LL;
  }
  __syncthreads();
  {
    int n = lane256;
    float q0 = qs[n], q1 = qs[256 + n], q2 = qs[512 + n];
    int m0 = quarter << 6;
    const float4* ka4 = reinterpret_cast<const float4*>(ks + m0);
    const float4* kb4 = reinterpret_cast<const float4*>(ks + 256 + m0);
    const float4* kc4 = reinterpret_cast<const float4*>(ks + 512 + m0);
    const float4* va4 = reinterpret_cast<const float4*>(vs + m0);
    const float4* vb4 = reinterpret_cast<const float4*>(vs + 256 + m0);
    const float4* vc4 = reinterpret_cast<const float4*>(vs + 512 + m0);
    const float4* mm4 = reinterpret_cast<const float4*>(Ms + m0);
    const float4* ll4 = reinterpret_cast<const float4*>(Ls + m0);
    float a0 = 0.f, a1 = 0.f, a2 = 0.f;
    #pragma unroll 4
    for (int j = 0; j < 16; ++j) {
      float4 ka = ka4[j], kbv = kb4[j], kc = kc4[j];
      float4 va = va4[j], vbv = vb4[j], vc = vc4[j];
      float4 mm = mm4[j], ll = ll4[j];
      float s, w;
      s = ka.x * q0 + kbv.x * q1 + kc.x * q2;
      w = exp2f(s - mm.x) * ll.x;
      a0 = fmaf(va.x, w, a0); a1 = fmaf(vbv.x, w, a1); a2 = fmaf(vc.x, w, a2);
      s = ka.y * q0 + kbv.y * q1 + kc.y * q2;
      w = exp2f(s - mm.y) * ll.y;
      a0 = fmaf(va.y, w, a0); a1 = fmaf(vbv.y, w, a1); a2 = fmaf(vc.y, w, a2);
      s = ka.z * q0 + kbv.z * q1 + kc.z * q2;
      w = exp2f(s - mm.z) * ll.z;
      a0 = fmaf(va.z, w, a0); a1 = fmaf(vbv.z, w, a1); a2 = fmaf(vc.z, w, a2);
      s = ka.w * q0 + kbv.w * q1 + kc.w * q2;
      w = exp2f(s - mm.w) * ll.w;
      a0 = fmaf(va.w, w, a0); a1 = fmaf(vbv.w, w, a1); a2 = fmaf(vc.w, w, a2);
    }
    Oq[tid] = a0;
    Oq[1024 + tid] = a1;
    Oq[2048 + tid] = a2;
  }
  __syncthreads();
  if (tid < 768) {
    int c = tid >> 8, n = tid & 255;
    int cb_ = c << 10;
    y2s[tid] += Oq[cb_ + n] + Oq[cb_ + 256 + n] + Oq[cb_ + 512 + n] + Oq[cb_ + 768 + n];
  }
  __syncthreads();
  float sc[3] = {0.f, 0.f, 0.f}, sq[3] = {0.f, 0.f, 0.f};
  int p = tid;
  if (p < 144) {
    int py = p / 12, px = p - py * 12;
    float a1[3], a2[3];
    #pragma unroll
    for (int c = 0; c < 3; ++c) { a1[c] = cb1[c]; a2[c] = cb2[c]; }
    #pragma unroll
    for (int ci = 0; ci < 3; ++ci) {
      #pragma unroll
      for (int ky = 0; ky < 5; ++ky) {
        const float* row = &y2s[ci * 256 + (py + ky) * 16 + px];
        #pragma unroll
        for (int c = 0; c < 3; ++c) {
          #pragma unroll
          for (int kx = 0; kx < 5; ++kx) {
            a1[c] = fmaf(row[kx], cw1[c * 75 + ci * 25 + ky * 5 + kx], a1[c]);
            a2[c] = fmaf(row[kx], cw2[c * 75 + ci * 25 + ky * 5 + kx], a2[c]);
          }
        }
      }
    }
    float wy = (float)(((py + 1) * r + 11) / 12 - (py * r + 11) / 12);
    float wx = (float)(((px + 1) * r + 11) / 12 - (px * r + 11) / 12);
    float wgt = wy * wx;
    #pragma unroll
    for (int c = 0; c < 3; ++c) {
      yu_out[(size_t)(b * 3 + c) * 144 + p] = make_float2(a1[c], a2[c]);
      sc[c] += a1[c] * wgt;
      sq[c] += a1[c] * a1[c] * wgt;
    }
  }
  #pragma unroll
  for (int off = 32; off; off >>= 1) {
    #pragma unroll
    for (int c = 0; c < 3; ++c) {
      sc[c] += __shfl_down(sc[c], off);
      sq[c] += __shfl_down(sq[c], off);
    }
  }
  int wid = tid >> 6, lane = tid & 63;
  if (lane == 0) {
    #pragma unroll
    for (int c = 0; c < 3; ++c) { redS[wid][c] = sc[c]; redQ[wid][c] = sq[c]; }
  }
  __syncthreads();
  if (tid < 3) {
    int c = tid;
    float s1 = 0.f, s2 = 0.f;
    #pragma unroll
    for (int w = 0; w < 16; ++w) { s1 += redS[w][c]; s2 += redQ[w][c]; }
    int NTg = (int)gridDim.x;  // 32, one block per image -> plain store
    sums_out[(2 * c) * NTg + b] = s1;
    sums_out[(2 * c + 1) * NTg + b] = s2;
  }
}

// ---- attn8 (rank-144) + conv9 fused, packed float4 operands, 32 blocks ----
__global__ __launch_bounds__(256) void attn144c9_k(
    const float2* __restrict__ yin, const float* __restrict__ sums,
    const float* __restrict__ inp, const float* __restrict__ lnp,
    const float* __restrict__ bnp, const float* __restrict__ bnw,
    const float* __restrict__ bnb, const float* __restrict__ p1p,
    const float* __restrict__ p2p,
    const float* __restrict__ qw, const float* __restrict__ qb,
    const float* __restrict__ kw, const float* __restrict__ kb,
    const float* __restrict__ vw, const float* __restrict__ vb,
    const float* __restrict__ cw1, const float* __restrict__ cb1,
    const float* __restrict__ cw2, const float* __restrict__ cb2,
    float2* __restrict__ yu_out, float* __restrict__ sums_out) {
  __shared__ float pA[3], pB[3], pP2v, sred[12];
  __shared__ float y2[432], Osh[432];
  __shared__ __align__(16) float4 qkp[144];  // (q0,q1,q2, wn)
  __shared__ __align__(16) float4 ksp[144];  // (k*log2e x3, M_row)
  __shared__ __align__(16) float4 vsp[144];  // (v0,v1,v2, wn/l)
  int b = blockIdx.x;
  int t = threadIdx.x;
  compute_AB_P(sums, b, 32, 1, 1024.f, 32.f, inp, lnp, bnp, bnw, bnb, p1p,
               p2p, pA, pB, &pP2v, sred);
  for (int idx = t; idx < 432; idx += 256) {
    int c = idx / 144, j = idx - c * 144;
    float2 v = yin[(size_t)(b * 3 + c) * 144 + j];
    y2[idx] = pA[c] * v.x + pB[c] + pP2v * v.y;
  }
  __syncthreads();
  if (t < 144) {
    int j = t;
    float y0 = y2[j], y1 = y2[144 + j], y2v = y2[288 + j];
    int jy = j / 12, jx = j - jy * 12;
    int cy = (8 * (jy + 1) + 2) / 3 - (8 * jy + 2) / 3;
    int cx = (8 * (jx + 1) + 2) / 3 - (8 * jx + 2) / 3;
    float wnv = (float)(cy * cx);
    qkp[j] = make_float4(
        qb[0] + qw[0] * y0 + qw[1] * y1 + qw[2] * y2v,
        qb[1] + qw[3] * y0 + qw[4] * y1 + qw[5] * y2v,
        qb[2] + qw[6] * y0 + qw[7] * y1 + qw[8] * y2v, wnv);
    ksp[j] = make_float4(
        (kb[0] + kw[0] * y0 + kw[1] * y1 + kw[2] * y2v) * LOG2E,
        (kb[1] + kw[3] * y0 + kw[4] * y1 + kw[5] * y2v) * LOG2E,
        (kb[2] + kw[6] * y0 + kw[7] * y1 + kw[8] * y2v) * LOG2E, 0.f);
    vsp[j] = make_float4(
        vb[0] + vw[0] * y0 + vw[1] * y1 + vw[2] * y2v,
        vb[1] + vw[3] * y0 + vw[4] * y1 + vw[5] * y2v,
        vb[2] + vw[6] * y0 + vw[7] * y1 + vw[8] * y2v, 0.f);
  }
  __syncthreads();
  if (t < 144) {
    int m = t;
    float4 kk = ksp[m];
    float mr = -1e30f;
    #pragma unroll 4
    for (int nn = 0; nn < 144; ++nn) {
      float4 q4 = qkp[nn];
      float s = kk.x * q4.x + kk.y * q4.y + kk.z * q4.z;
      mr = fmaxf(mr, s);
    }
    float l = 0.f;
    #pragma unroll 4
    for (int nn = 0; nn < 144; ++nn) {
      float4 q4 = qkp[nn];
      float s = kk.x * q4.x + kk.y * q4.y + kk.z * q4.z;
      l += q4.w * exp2f(s - mr);
    }
    ksp[m].w = mr;
    vsp[m].w = qkp[m].w / l;  // wn[m] / l[m]
  }
  __syncthreads();
  if (t < 144) {
    int nq = t;
    float4 q4 = qkp[nq];
    float a0 = 0.f, a1 = 0.f, a2 = 0.f;
    #pragma unroll 4
    for (int m = 0; m < 144; ++m) {
      float4 k4 = ksp[m];
      float4 v4 = vsp[m];
      float s = k4.x * q4.x + k4.y * q4.y + k4.z * q4.z;
      float w = exp2f(s - k4.w) * v4.w;
      a0 = fmaf(v4.x, w, a0);
      a1 = fmaf(v4.y, w, a1);
      a2 = fmaf(v4.z, w, a2);
    }
    Osh[nq] = a0 + y2[nq];
    Osh[144 + nq] = a1 + y2[144 + nq];
    Osh[288 + nq] = a2 + y2[288 + nq];
  }
  __syncthreads();
  // conv9: 12-grid upsampled to 32, 5x5 valid -> 28x28, r=64
  float sc[3] = {0.f, 0.f, 0.f}, sq[3] = {0.f, 0.f, 0.f};
  for (int o = t; o < 784; o += 256) {
    int py = o / 28, px = o - py * 28;
    float a1[3], a2[3];
    #pragma unroll
    for (int c = 0; c < 3; ++c) { a1[c] = cb1[c]; a2[c] = cb2[c]; }
    #pragma unroll
    for (int ci = 0; ci < 3; ++ci) {
      const float* obase = &Osh[ci * 144];
      #pragma unroll
      for (int ky = 0; ky < 5; ++ky) {
        int sy = ((py + ky) * 12) >> 5;
        const float* orow = obase + sy * 12;
        #pragma unroll
        for (int kx = 0; kx < 5; ++kx) {
          int sx = ((px + kx) * 12) >> 5;
          float v = orow[sx];
          #pragma unroll
          for (int c = 0; c < 3; ++c) {
            a1[c] = fmaf(v, cw1[c * 75 + ci * 25 + ky * 5 + kx], a1[c]);
            a2[c] = fmaf(v, cw2[c * 75 + ci * 25 + ky * 5 + kx], a2[c]);
          }
        }
      }
    }
    float wy = (float)(((py + 1) * 64 + 27) / 28 - (py * 64 + 27) / 28);
    float wx = (float)(((px + 1) * 64 + 27) / 28 - (px * 64 + 27) / 28);
    float wgt = wy * wx;
    #pragma unroll
    for (int c = 0; c < 3; ++c) {
      yu_out[((size_t)(b * 3 + c) * 28 + py) * 28 + px] = make_float2(a1[c], a2[c]);
      sc[c] += a1[c] * wgt;
      sq[c] += a1[c] * a1[c] * wgt;
    }
  }
  STATS_REDUCE_STORE(sc, sq, sums_out, b)
}

// ---- final: affine + p2*u2 + tanh -> out; 2048 blocks, float4 stores ----
__global__ __launch_bounds__(256) void elem_final(
    const float2* __restrict__ yu, const float* __restrict__ sums,
    const float* __restrict__ inp, const float* __restrict__ lnp,
    const float* __restrict__ bnp, const float* __restrict__ bnw,
    const float* __restrict__ bnb, const float* __restrict__ p1p,
    const float* __restrict__ p2p, float* __restrict__ out, int S,
    int pNT, int pT) {
  __shared__ float pA[3], pB[3], pP2v, sred[12];
  int bid = xcd_swz();
  int n = bid >> 6;
  int part = bid & 63;
  compute_AB_P(sums, n, pNT, pT, 65536.f, 32.f, inp, lnp, bnp, bnw, bnb, p1p,
               p2p, pA, pB, &pP2v, sred);
  int p0 = (part << 10) + ((int)threadIdx.x << 2);
  int oy = p0 >> 8;
  int oxb = p0 & 255;
  int sy = ((oy * S) >> 8) * S;
  int si0 = sy + ((oxb * S) >> 8);
  int si1 = sy + (((oxb + 1) * S) >> 8);
  int si2 = sy + (((oxb + 2) * S) >> 8);
  int si3 = sy + (((oxb + 3) * S) >> 8);
  size_t ybase = (size_t)n * 3 * S * S;
  #pragma unroll
  for (int c = 0; c < 3; ++c) {
    const float2* yp = yu + ybase + (size_t)c * S * S;
    float2 v0 = yp[si0], v1 = yp[si1], v2 = yp[si2], v3 = yp[si3];
    float4 r;
    r.x = tanhf(pA[c] * v0.x + pB[c] + pP2v * v0.y);
    r.y = tanhf(pA[c] * v1.x + pB[c] + pP2v * v1.y);
    r.z = tanhf(pA[c] * v2.x + pB[c] + pP2v * v2.y);
    r.w = tanhf(pA[c] * v3.x + pB[c] + pP2v * v3.y);
    *reinterpret_cast<float4*>(&out[((size_t)(n * 3 + c) << 16) + p0]) = r;
  }
}

#define NPX nullptr, nullptr, nullptr, nullptr, nullptr, nullptr, nullptr, \
            nullptr, nullptr, 0, 0, 0, 0, 0

extern "C" void kernel_launch(void* const* d_in, const int* in_sizes, int n_in,
                              void* d_out, int out_size, void* d_ws, size_t ws_size,
                              hipStream_t stream) {
  const float* x       = (const float*)d_in[0];
  const float* noise_z = (const float*)d_in[1];
  const float* lin_w   = (const float*)d_in[2];
  const float* lin_b   = (const float*)d_in[3];
  const float* conv_w  = (const float*)d_in[4];
  const float* conv_b  = (const float*)d_in[5];
  const float* conv2_w = (const float*)d_in[6];
  const float* conv2_b = (const float*)d_in[7];
  const float* q_w     = (const float*)d_in[8];
  const float* q_b     = (const float*)d_in[9];
  const float* k_w     = (const float*)d_in[10];
  const float* k_b     = (const float*)d_in[11];
  const float* v_w     = (const float*)d_in[12];
  const float* v_b     = (const float*)d_in[13];
  const float* in_p    = (const float*)d_in[14];
  const float* ln_p    = (const float*)d_in[15];
  const float* bn_p    = (const float*)d_in[16];
  const float* bn_w    = (const float*)d_in[17];
  const float* bn_b    = (const float*)d_in[18];
  const float* p1      = (const float*)d_in[19];
  const float* p2      = (const float*)d_in[20];
  float* out = (float*)d_out;

  float* ws = (float*)d_ws;
  size_t off = 0;
  auto alloc = [&](size_t nf) { float* p = ws + off; off += nf; return p; };
  // per-stage partial stats, planar [6][NT]; NT = producer grid size
  float* PS    = alloc(27264);
  float* PS2   = PS;            // conv2:  NT=1024
  float* PS3   = PS + 6144;     // conv3:  NT=2048
  float* PS4   = PS + 18432;    // conv4:  NT=512
  float* PS5   = PS + 21504;    // conv5:  NT=128
  float* PS6   = PS + 22272;    // conv6:  NT=64
  float* PS6a  = PS + 22656;    // attn6:  NT=32
  float* PS7a  = PS + 22848;    // attn7:  NT=32
  float* PS9   = PS + 23040;    // attn144c9: NT=32
  float* PS10  = PS + 23424;    // conv10: NT=128
  float* PS11  = PS + 24192;    // conv11: NT=512
  float* P45  = alloc(393216);
  float2* YU2 = (float2*)alloc(12192768);
  float2* PA  = (float2*)alloc(3145728);
  float2* PB  = (float2*)alloc(3145728);
  float* Mp   = alloc(131072);
  float* Lp   = alloc(131072);
  float* NB0  = alloc(12288);
  float* LIN  = alloc(768);

  const float* nul = nullptr;
  const float2* nul2 = nullptr;

  linear_wave<<<192, 256, 0, stream>>>(noise_z, lin_w, lin_b, LIN);
  noise_rest<<<1, 256, 0, stream>>>(LIN, conv_w, conv_b, conv2_w, conv2_b,
      in_p, ln_p, bn_p, bn_w, bn_b, p1, p2, NB0);

  // conv2: x -> YU2 (S=252, r=256), 64x32 tile, async global->LDS staging
  conv_up_t<0, 32><<<1024, 256, 0, stream>>>(x, nul2, YU2, conv_w + 450,
      conv_b + 6, conv2_w + 450, conv2_b + 6, PS2, 256, 252, 256, 4, 8,
      NPX);
  // conv3: fused(b2) YU2 -> PA (S=128), 32x8 tile; prev Sp=252, logrp=8
  conv_dn_t<1, false><<<2048, 256, 0, stream>>>(nul, YU2, PA,
      conv_w + 675, conv_b + 9, conv2_w + 675, conv2_b + 9, PS3,
      256, 128, 252, 7, 4, 16,
      PS2, in_p + 6, ln_p + 6, bn_p + 6, bn_w + 6, bn_b + 6, p1 + 2,
      p2 + 2, nul, 32, 252, 8, 1024, 32);
  // conv4: fused(b3) PA -> PB (S=64); prev identity
  conv_dn_t<1, true><<<512, 256, 0, stream>>>(nul, PA, PB,
      conv_w + 900, conv_b + 12, conv2_w + 900, conv2_b + 12, PS4,
      128, 64, 124, 6, 2, 8,
      PS3, in_p + 9, ln_p + 9, bn_p + 9, bn_w + 9, bn_b + 9, p1 + 3,
      p2 + 3, nul, 32, 128, 7, 2048, 64);
  // conv5: fused(b4)+noise PB -> PA (S=32); prev identity
  conv_dn_t<1, true><<<128, 256, 0, stream>>>(nul, PB, PA,
      conv_w + 1125, conv_b + 15, conv2_w + 1125, conv2_b + 15, PS5,
      64, 32, 60, 5, 1, 4,
      PS4, in_p + 12, ln_p + 12, bn_p + 12, bn_w + 12, bn_b + 12, p1 + 4,
      p2 + 4, NB0, 32, 64, 6, 512, 16);
  // attn5 (HW=1024) on PA (S=32) -> partials P45
  attn_rows_f<<<512, 256, 0, stream>>>(PA, PS5, in_p + 15, ln_p + 15,
      bn_p + 15, bn_w + 15, bn_b + 15, p1 + 5, p2 + 5,
      q_w + 45, q_b + 15, k_w + 45, k_b + 15, Mp, Lp, 32, 128, 4);
  attn_out_f<<<512, 256, 0, stream>>>(PA, PS5, in_p + 15, ln_p + 15,
      bn_p + 15, bn_w + 15, bn_b + 15, p1 + 5, p2 + 5,
      q_w + 45, q_b + 15, k_w + 45, k_b + 15, v_w + 45, v_b + 15, Mp, Lp, P45,
      32, 128, 4);
  // conv6: SUM4 staging from P45 -> PB (S=16)
  conv_dn_t<2, false><<<64, 256, 0, stream>>>(P45, nul2, PB,
      conv_w + 1350, conv_b + 18, conv2_w + 1350, conv2_b + 18, PS6,
      32, 16, 28, 4, 1, 2, NPX);
  // attn6 (HW=256) on PB (S=16) + conv7 (r=16) -> PA (S=12)
  attn256_conv<<<32, 1024, 0, stream>>>(PB, PS6, in_p + 18, ln_p + 18,
      bn_p + 18, bn_w + 18, bn_b + 18, p1 + 6, p2 + 6,
      q_w + 54, q_b + 18, k_w + 54, k_b + 18, v_w + 54, v_b + 18,
      conv_w + 1575, conv_b + 21, conv2_w + 1575, conv2_b + 21,
      PA, PS6a, 16, 16, 64, 2);
  // attn7 (HW=256) on PA (S=12) + conv8 (r=32) -> PB (S=12)
  attn256_conv<<<32, 1024, 0, stream>>>(PA, PS6a, in_p + 21, ln_p + 21,
      bn_p + 21, bn_w + 21, bn_b + 21, p1 + 7, p2 + 7,
      q_w + 63, q_b + 21, k_w + 63, k_b + 21, v_w + 63, v_b + 21,
      conv_w + 1800, conv_b + 24, conv2_w + 1800, conv2_b + 24,
      PB, PS7a, 12, 32, 32, 1);
  // attn8 (rank-144, packed) + conv9 fused: PB(144) -> PA (S=28, r=64)
  attn144c9_k<<<32, 256, 0, stream>>>(PB, PS7a, in_p + 24, ln_p + 24,
      bn_p + 24, bn_w + 24, bn_b + 24, p1 + 8, p2 + 8,
      q_w + 72, q_b + 24, k_w + 72, k_b + 24, v_w + 72, v_b + 24,
      conv_w + 2025, conv_b + 27, conv2_w + 2025, conv2_b + 27,
      PA, PS9);
  // conv10: fused(b9) PA -> PB (S=60); prev Sp=28, logrp=6; stats NT=32,T=1
  conv_up_t<1, 16><<<128, 256, 0, stream>>>(nul, PA, PB, conv_w + 2250,
      conv_b + 30, conv2_w + 2250, conv2_b + 30, PS10, 64, 60, 128, 1, 4,
      PS9, in_p + 27, ln_p + 27, bn_p + 27, bn_w + 27, bn_b + 27,
      p1 + 9, p2 + 9, nul, 32, 28, 6, 32, 1);
  // conv11: fused(b10) PB -> YU2 (S=124); prev Sp=60, logrp=7
  conv_up_t<1, 16><<<512, 256, 0, stream>>>(nul, PB, YU2, conv_w + 2475,
      conv_b + 33, conv2_w + 2475, conv2_b + 33, PS11, 128, 124, 256, 2, 8,
      PS10, in_p + 30, ln_p + 30, bn_p + 30, bn_w + 30, bn_b + 30,
      p1 + 10, p2 + 10, nul, 32, 60, 7, 128, 4);
  // final: tanh -> out (2048 blocks, 4 px/thread, float4 stores)
  elem_final<<<2048, 256, 0, stream>>>(YU2, PS11, in_p + 33, ln_p + 33,
      bn_p + 33, bn_w + 33, bn_b + 33, p1 + 11, p2 + 11, out, 124, 512, 16);
}

// Round 11
// 406.595 us; speedup vs baseline: 1.0321x; 1.0321x over previous
//
#include <hip/hip_runtime.h>
#include <math.h>

#define EPS 1e-5f
#define LOG2E 1.44269504088896340736f

#define AS_GLOBAL __attribute__((address_space(1)))
#define AS_LDS    __attribute__((address_space(3)))

// ---- shared affine-fold helper: A,B from sums (instance+batch norm + p1) ----
__device__ __forceinline__ float2 ab_from(float s1, float s2, float bs, float bs2,
    float hw, float Nf, float si_, float sb, float bnw_c, float bnb_c, float p1v) {
  float inv = 1.0f / hw;
  float mi = s1 * inv, vi = s2 * inv - mi * mi;
  float ri = rsqrtf(vi + EPS);
  float invb = 1.0f / (Nf * hw);
  float mb = bs * invb, vb = bs2 * invb - mb * mb;
  float rb = rsqrtf(vb + EPS);
  float A = 1.0f + si_ * ri + sb * rb * bnw_c;
  float B = -(si_ * ri * mi + sb * rb * bnw_c * mb) + sb * bnb_c;
  return make_float2(A * p1v, B * p1v);
}

// Partial-stats layout: P[c2][NT] planar, c2 = 2*c (+1 for sumsq), NT = producer grid.
__device__ __forceinline__ void compute_AB_P(
    const float* __restrict__ P, int n, int NT, int T, float hw, float Nf,
    const float* __restrict__ inp, const float* __restrict__ lnp,
    const float* __restrict__ bnp, const float* __restrict__ bnw,
    const float* __restrict__ bnb, const float* __restrict__ p1p,
    const float* __restrict__ p2p, float* pA, float* pB, float* pP2,
    float* sred /* __shared__ float[12] */) {
  int t = threadIdx.x;
  if (t == 0) *pP2 = p2p[0];
  if (t < 192) {
    int c2 = t >> 5, l = t & 31;
    const float* pp = P + c2 * NT;
    float aAll = 0.f, aOwn = 0.f;
    int base = n * T;
    #pragma unroll 4
    for (int i = l; i < NT; i += 32) {
      float v = pp[i];
      aAll += v;
      if ((unsigned)(i - base) < (unsigned)T) aOwn += v;
    }
    #pragma unroll
    for (int off = 16; off; off >>= 1) {
      aAll += __shfl_down(aAll, off, 32);
      aOwn += __shfl_down(aOwn, off, 32);
    }
    if (l == 0) { sred[c2] = aOwn; sred[6 + c2] = aAll; }
  }
  __syncthreads();
  if (t < 3) {
    int c = t;
    float si_ = inp[0] + inp[1] + inp[2] + lnp[0] + lnp[1] + lnp[2];
    float sb = bnp[0] + bnp[1] + bnp[2];
    float2 ab = ab_from(sred[2 * c], sred[2 * c + 1], sred[6 + 2 * c],
                        sred[6 + 2 * c + 1], hw, Nf, si_, sb, bnw[c], bnb[c],
                        p1p[0]);
    pA[c] = ab.x;
    pB[c] = ab.y;
  }
  __syncthreads();
}

// stats block-reduce (256 threads, all must participate): plain store, NO atomics.
#define STATS_REDUCE_STORE(scv, sqv, sumsp, bidv)                             \
  {                                                                           \
    _Pragma("unroll")                                                         \
    for (int off = 32; off; off >>= 1) {                                      \
      _Pragma("unroll")                                                       \
      for (int c = 0; c < 3; ++c) {                                           \
        scv[c] += __shfl_down(scv[c], off);                                   \
        sqv[c] += __shfl_down(sqv[c], off);                                   \
      }                                                                       \
    }                                                                         \
    __shared__ float redS[4][3], redQ[4][3];                                  \
    int wid = threadIdx.x >> 6, lane = threadIdx.x & 63;                      \
    if (lane == 0) {                                                          \
      _Pragma("unroll")                                                       \
      for (int c = 0; c < 3; ++c) { redS[wid][c] = scv[c]; redQ[wid][c] = sqv[c]; } \
    }                                                                         \
    __syncthreads();                                                          \
    if (threadIdx.x < 3) {                                                    \
      int c = threadIdx.x;                                                    \
      int NTg = (int)gridDim.x;                                               \
      sumsp[(2 * c) * NTg + (bidv)] =                                         \
          redS[0][c] + redS[1][c] + redS[2][c] + redS[3][c];                  \
      sumsp[(2 * c + 1) * NTg + (bidv)] =                                     \
          redQ[0][c] + redQ[1][c] + redQ[2][c] + redQ[3][c];                  \
    }                                                                         \
  }

// XCD-aware bijective swizzle (grid must be a multiple of 8).
__device__ __forceinline__ int xcd_swz() {
  return ((int)(blockIdx.x & 7)) * ((int)gridDim.x >> 3) + ((int)blockIdx.x >> 3);
}

// ---- staging value loader ----
// MODE: 0=direct, 1=fused affine float2 (+noise), 2=sum4 partials, 3=gather small grid
template <int MODE, bool IDENT>
__device__ __forceinline__ float stage_val(
    const float* __restrict__ inb, size_t ps,
    const float2* __restrict__ pyu, size_t pbase,
    int Hin, int gy, int gx, int Sp, int logrp,
    const float* pA, const float* pB, float pP2v,
    const float* __restrict__ pnoise, int cc) {
  if (MODE == 1) {
    int gxs = IDENT ? gx : ((gx * Sp) >> logrp);
    int rbase = IDENT ? gy * Sp : ((gy * Sp) >> logrp) * Sp;
    float2 v = pyu[pbase + (size_t)cc * Sp * Sp + rbase + gxs];
    float val = pA[cc] * v.x + pB[cc] + pP2v * v.y;
    if (pnoise) val += pnoise[((size_t)cc * Hin + gy) * Hin + gx];
    return val;
  } else if (MODE == 2) {
    size_t idx = ((size_t)cc * Hin + gy) * Hin + gx;
    return inb[idx] + inb[idx + ps] + inb[idx + 2 * ps] + inb[idx + 3 * ps];
  } else if (MODE == 3) {
    int gys = (gy * Sp) >> logrp, gxs = (gx * Sp) >> logrp;
    return inb[(cc * Sp + gys) * Sp + gxs];
  } else {
    return inb[((size_t)cc * Hin + gy) * Hin + gx];
  }
}

// ---- division-free 2D staging of a 3 x IHv x 68 tile ----
template <int MODE, bool IDENT, int IHv>
__device__ __forceinline__ void stage_tile(
    float* __restrict__ lin, const float* __restrict__ inb, size_t ps,
    const float2* __restrict__ pyu, size_t pbase,
    int Hin, int sy0, int sx0, int Sp, int logrp,
    const float* pA, const float* pB, float pP2v,
    const float* __restrict__ pnoise) {
  const int IW = 68;
  int colt = threadIdx.x & 63;
  int r4 = threadIdx.x >> 6;
  int gx = sx0 + colt; gx = gx < Hin ? gx : Hin - 1;
  #pragma unroll
  for (int cc = 0; cc < 3; ++cc) {
    #pragma unroll
    for (int rb = 0; rb < IHv / 4; ++rb) {
      int rr = r4 + (rb << 2);
      int gy = sy0 + rr; gy = gy < Hin ? gy : Hin - 1;
      lin[(cc * IHv + rr) * IW + colt] =
          stage_val<MODE, IDENT>(inb, ps, pyu, pbase, Hin, gy, gx, Sp, logrp,
                                 pA, pB, pP2v, pnoise, cc);
    }
  }
  for (int t = threadIdx.x; t < 3 * IHv * 4; t += 256) {
    int col2 = 64 + (t & 3);
    int rowlin = t >> 2;
    int cc = rowlin / IHv, rr = rowlin - cc * IHv;
    int gx2 = sx0 + col2; gx2 = gx2 < Hin ? gx2 : Hin - 1;
    int gy = sy0 + rr; gy = gy < Hin ? gy : Hin - 1;
    lin[(cc * IHv + rr) * IW + col2] =
        stage_val<MODE, IDENT>(inb, ps, pyu, pbase, Hin, gy, gx2, Sp, logrp,
                               pA, pB, pP2v, pnoise, cc);
  }
}

// ---- LDS-tiled upsample conv (S==hc): 64 x THv tile, TX=4, float2 out ----
template <int SMODE, int THv>
__global__ __launch_bounds__(256) void conv_up_t(
    const float* __restrict__ in, const float2* __restrict__ pyu,
    float2* __restrict__ yu,
    const float* __restrict__ w1, const float* __restrict__ b1,
    const float* __restrict__ w2, const float* __restrict__ b2,
    float* __restrict__ sums, int Hin, int S, int r, int tilesX, int tilesY,
    const float* __restrict__ psums,
    const float* __restrict__ pinp, const float* __restrict__ plnp,
    const float* __restrict__ pbnp, const float* __restrict__ pbnw,
    const float* __restrict__ pbnb, const float* __restrict__ pp1,
    const float* __restrict__ pp2, const float* __restrict__ pnoise,
    int pN, int Sp, int logrp, int pNT, int pT) {
  const int TW = 64, IW = 68, IH = THv + 4, NH = THv / 16;
  __shared__ float lin[3 * IH * IW];
  __shared__ float pA[3], pB[3], pP2v, sred[12];
  int bid = xcd_swz();
  int tpi = tilesX * tilesY;
  int n = bid / tpi;
  int trem = bid - n * tpi;
  int tyB = trem / tilesX, txB = trem - tyB * tilesX;
  int px0 = txB * TW, py0 = tyB * THv;
  const float* inb = in + (size_t)n * 3 * Hin * Hin;
  if (SMODE == 1) {
    compute_AB_P(psums, n, pNT, pT, (float)(Hin * Hin), (float)pN, pinp, plnp,
                 pbnp, pbnw, pbnb, pp1, pp2, pA, pB, &pP2v, sred);
    size_t pbase = (size_t)n * 3 * Sp * Sp;
    stage_tile<1, false, IH>(lin, nullptr, 0, pyu, pbase, Hin, py0, px0, Sp,
                             logrp, pA, pB, pP2v, pnoise);
  } else if (SMODE == 3) {
    const float* smallb = in + (size_t)n * 3 * Sp * Sp;
    stage_tile<3, false, IH>(lin, smallb, 0, nullptr, 0, Hin, py0, px0, Sp,
                             logrp, nullptr, nullptr, 0.f, nullptr);
  } else {
    if (px0 + IW <= Hin && py0 + IH <= Hin) {
      for (int t4 = threadIdx.x; t4 < 3 * IH * 17; t4 += 256) {
        int cc = t4 / (IH * 17);
        int rem = t4 - cc * (IH * 17);
        int rr = rem / 17, j = rem - rr * 17;
        const float* src = inb + ((size_t)cc * Hin + py0 + rr) * Hin + px0 + 4 * j;
        int base = t4 - (threadIdx.x & 63);  // wave-uniform float4 index
        __builtin_amdgcn_global_load_lds(
            (const AS_GLOBAL void*)src,
            (AS_LDS void*)(lin + 4 * base), 16, 0, 0);
      }
    } else {
      stage_tile<0, false, IH>(lin, inb, 0, nullptr, 0, Hin, py0, px0, 0, 0,
                               nullptr, nullptr, 0.f, nullptr);
    }
  }
  __syncthreads();
  int tx = threadIdx.x & 15, ty = threadIdx.x >> 4;
  int lx0 = tx * 4;
  float a1[NH][3][4], a2[NH][3][4];
  #pragma unroll
  for (int h = 0; h < NH; ++h) {
    #pragma unroll
    for (int c = 0; c < 3; ++c) {
      float bb1 = b1[c], bb2 = b2[c];
      #pragma unroll
      for (int x = 0; x < 4; ++x) { a1[h][c][x] = bb1; a2[h][c][x] = bb2; }
    }
  }
  #pragma unroll 1
  for (int ci = 0; ci < 3; ++ci) {
    const float* wp1 = w1 + ci * 25;
    const float* wp2 = w2 + ci * 25;
    #pragma unroll
    for (int h = 0; h < NH; ++h) {
      const float* lrow = lin + (ci * IH + ty + 16 * h) * IW + lx0;
      float v[5][8];
      #pragma unroll
      for (int ky = 0; ky < 5; ++ky) {
        #pragma unroll
        for (int j = 0; j < 8; ++j) { v[ky][j] = lrow[ky * IW + j]; }
      }
      #pragma unroll
      for (int ky = 0; ky < 5; ++ky) {
        #pragma unroll
        for (int c = 0; c < 3; ++c) {
          #pragma unroll
          for (int kx = 0; kx < 5; ++kx) {
            float wa = wp1[c * 75 + ky * 5 + kx];
            float wb = wp2[c * 75 + ky * 5 + kx];
            #pragma unroll
            for (int x = 0; x < 4; ++x) {
              a1[h][c][x] = fmaf(v[ky][kx + x], wa, a1[h][c][x]);
              a2[h][c][x] = fmaf(v[ky][kx + x], wb, a2[h][c][x]);
            }
          }
        }
      }
    }
  }
  float sc[3] = {0.f, 0.f, 0.f}, sq[3] = {0.f, 0.f, 0.f};
  int hc = S;
  int px = px0 + lx0;
  #pragma unroll
  for (int h = 0; h < NH; ++h) {
    int py = py0 + ty + 16 * h;
    bool valid = (py < S) && (px < S);
    if (valid) {
      float wy = (float)(((py + 1) * r + hc - 1) / hc - (py * r + hc - 1) / hc);
      float wx[4];
      #pragma unroll
      for (int x = 0; x < 4; ++x) {
        int pxx = px + x;
        wx[x] = (float)(((pxx + 1) * r + hc - 1) / hc - (pxx * r + hc - 1) / hc);
      }
      #pragma unroll
      for (int c = 0; c < 3; ++c) {
        size_t idx = ((size_t)(n * 3 + c) * S + py) * S + px;
        float2* yp = yu + idx;
        *reinterpret_cast<float4*>(yp) =
            make_float4(a1[h][c][0], a2[h][c][0], a1[h][c][1], a2[h][c][1]);
        *reinterpret_cast<float4*>(yp + 2) =
            make_float4(a1[h][c][2], a2[h][c][2], a1[h][c][3], a2[h][c][3]);
        #pragma unroll
        for (int x = 0; x < 4; ++x) {
          float wgt = wy * wx[x];
          sc[c] += a1[h][c][x] * wgt;
          sq[c] += a1[h][c][x] * a1[h][c][x] * wgt;
        }
      }
    }
  }
  STATS_REDUCE_STORE(sc, sq, sums, bid)
}

// ---- LDS-tiled downsample conv (ratio<2.05): 32 x 8 tile, float2 out ----
template <int SMODE, bool IDENT>
__global__ __launch_bounds__(256) void conv_dn_t(
    const float* __restrict__ in, const float2* __restrict__ pyu,
    float2* __restrict__ yu,
    const float* __restrict__ w1, const float* __restrict__ b1,
    const float* __restrict__ w2, const float* __restrict__ b2,
    float* __restrict__ sums, int Hin, int S, int hc, int logr,
    int tilesX, int tilesY,
    const float* __restrict__ psums,
    const float* __restrict__ pinp, const float* __restrict__ plnp,
    const float* __restrict__ pbnp, const float* __restrict__ pbnw,
    const float* __restrict__ pbnb, const float* __restrict__ pp1,
    const float* __restrict__ pp2, const float* __restrict__ pnoise,
    int pN, int Sp, int logrp, int pNT, int pT) {
  const int TW = 32, TH = 8, IW = 68, IH = 20;
  __shared__ float lin[3 * IH * IW];
  __shared__ float pA[3], pB[3], pP2v, sred[12];
  int bid = xcd_swz();
  int tpi = tilesX * tilesY;
  int n = bid / tpi;
  int trem = bid - n * tpi;
  int tyB = trem / tilesX, txB = trem - tyB * tilesX;
  int px0 = txB * TW, py0 = tyB * TH;
  int sy0 = (py0 * hc) >> logr, sx0 = (px0 * hc) >> logr;
  const float* inb = in + (size_t)n * 3 * Hin * Hin;
  if (SMODE == 1) {
    compute_AB_P(psums, n, pNT, pT, (float)(Hin * Hin), (float)pN, pinp, plnp,
                 pbnp, pbnw, pbnb, pp1, pp2, pA, pB, &pP2v, sred);
    size_t pbase = (size_t)n * 3 * Sp * Sp;
    stage_tile<1, IDENT, IH>(lin, nullptr, 0, pyu, pbase, Hin, sy0, sx0, Sp,
                             logrp, pA, pB, pP2v, pnoise);
  } else if (SMODE == 2) {
    size_t ps = (size_t)96 * Hin * Hin;
    stage_tile<2, false, IH>(lin, inb, ps, nullptr, 0, Hin, sy0, sx0, 0, 0,
                             nullptr, nullptr, 0.f, nullptr);
  } else {
    stage_tile<0, false, IH>(lin, inb, 0, nullptr, 0, Hin, sy0, sx0, 0, 0,
                             nullptr, nullptr, 0.f, nullptr);
  }
  __syncthreads();
  int tx = threadIdx.x & 31, ty = threadIdx.x >> 5;
  int px = px0 + tx, py = py0 + ty;
  int sxl = ((px * hc) >> logr) - sx0;
  int syl = ((py * hc) >> logr) - sy0;
  float a1[3], a2[3];
  #pragma unroll
  for (int c = 0; c < 3; ++c) { a1[c] = b1[c]; a2[c] = b2[c]; }
  #pragma unroll
  for (int ci = 0; ci < 3; ++ci) {
    const float* lrow = lin + (ci * IH + syl) * IW + sxl;
    const float* wp1 = w1 + ci * 25;
    const float* wp2 = w2 + ci * 25;
    #pragma unroll
    for (int ky = 0; ky < 5; ++ky) {
      float v[5];
      #pragma unroll
      for (int j = 0; j < 5; ++j) { v[j] = lrow[ky * IW + j]; }
      #pragma unroll
      for (int c = 0; c < 3; ++c) {
        #pragma unroll
        for (int kx = 0; kx < 5; ++kx) {
          a1[c] = fmaf(v[kx], wp1[c * 75 + ky * 5 + kx], a1[c]);
          a2[c] = fmaf(v[kx], wp2[c * 75 + ky * 5 + kx], a2[c]);
        }
      }
    }
  }
  float sc[3] = {0.f, 0.f, 0.f}, sq[3] = {0.f, 0.f, 0.f};
  bool valid = (py < S) && (px < S);
  if (valid) {
    #pragma unroll
    for (int c = 0; c < 3; ++c) {
      size_t idx = ((size_t)(n * 3 + c) * S + py) * S + px;
      yu[idx] = make_float2(a1[c], a2[c]);
      sc[c] += a1[c];
      sq[c] += a1[c] * a1[c];
    }
  }
  STATS_REDUCE_STORE(sc, sq, sums, bid)
}

// ---- Linear 512->768: one wave per output row, coalesced float4 ----
__global__ __launch_bounds__(256) void linear_wave(
    const float* __restrict__ z, const float* __restrict__ w,
    const float* __restrict__ b, float* __restrict__ out) {
  int row = (blockIdx.x << 2) + (threadIdx.x >> 6);
  int lane = threadIdx.x & 63;
  const float4* wr = reinterpret_cast<const float4*>(w + (size_t)row * 512);
  const float4* zz = reinterpret_cast<const float4*>(z);
  float acc = 0.f;
  #pragma unroll
  for (int i = 0; i < 2; ++i) {
    float4 wv = wr[lane + 64 * i];
    float4 zv = zz[lane + 64 * i];
    acc += wv.x * zv.x + wv.y * zv.y + wv.z * zv.z + wv.w * zv.w;
  }
  #pragma unroll
  for (int off = 32; off; off >>= 1) acc += __shfl_down(acc, off);
  if (lane == 0) out[row] = acc + b[row];
}

// ---- noise conv path (blocks 0,1) in one block, L0 from global ----
__global__ __launch_bounds__(256) void noise_rest(
    const float* __restrict__ L0g,
    const float* __restrict__ cw, const float* __restrict__ cb,
    const float* __restrict__ c2w, const float* __restrict__ c2b,
    const float* __restrict__ inp, const float* __restrict__ lnp,
    const float* __restrict__ bnp, const float* __restrict__ bnw,
    const float* __restrict__ bnb, const float* __restrict__ p1p,
    const float* __restrict__ p2p, float* __restrict__ nb0) {
  __shared__ float L0[768];
  __shared__ float ys0[432], u20[432];
  __shared__ float buf1[3072];
  __shared__ float ys1[2352], u21[2352];
  __shared__ float redS[4][3], redQ[4][3];
  __shared__ float AB[6];
  int tid = threadIdx.x;
  for (int t = tid; t < 768; t += 256) { L0[t] = L0g[t]; }
  __syncthreads();
  // ---- conv0: (3,16,16) -> S=12, r=32 ----
  {
    float sc[3] = {0, 0, 0}, sq[3] = {0, 0, 0};
    for (int p = tid; p < 144; p += 256) {
      int py = p / 12, px = p - py * 12;
      float a1[3], a2[3];
      #pragma unroll
      for (int c = 0; c < 3; ++c) { a1[c] = cb[c]; a2[c] = c2b[c]; }
      for (int ci = 0; ci < 3; ++ci) {
        #pragma unroll
        for (int ky = 0; ky < 5; ++ky) {
          const float* row = &L0[ci * 256 + (py + ky) * 16 + px];
          #pragma unroll
          for (int c = 0; c < 3; ++c) {
            #pragma unroll
            for (int kx = 0; kx < 5; ++kx) {
              a1[c] = fmaf(row[kx], cw[c * 75 + ci * 25 + ky * 5 + kx], a1[c]);
              a2[c] = fmaf(row[kx], c2w[c * 75 + ci * 25 + ky * 5 + kx], a2[c]);
            }
          }
        }
      }
      int wy = ((py + 1) * 32 + 11) / 12 - (py * 32 + 11) / 12;
      int wx = ((px + 1) * 32 + 11) / 12 - (px * 32 + 11) / 12;
      float wgt = (float)(wy * wx);
      #pragma unroll
      for (int c = 0; c < 3; ++c) {
        ys0[c * 144 + p] = a1[c];
        u20[c * 144 + p] = a2[c];
        sc[c] += a1[c] * wgt;
        sq[c] += a1[c] * a1[c] * wgt;
      }
    }
    #pragma unroll
    for (int off = 32; off; off >>= 1) {
      #pragma unroll
      for (int c = 0; c < 3; ++c) {
        sc[c] += __shfl_down(sc[c], off);
        sq[c] += __shfl_down(sq[c], off);
      }
    }
    int wid = tid >> 6, lane = tid & 63;
    if (lane == 0) {
      #pragma unroll
      for (int c = 0; c < 3; ++c) { redS[wid][c] = sc[c]; redQ[wid][c] = sq[c]; }
    }
    __syncthreads();
    if (tid < 3) {
      int c = tid;
      float s1 = redS[0][c] + redS[1][c] + redS[2][c] + redS[3][c];
      float s2 = redQ[0][c] + redQ[1][c] + redQ[2][c] + redQ[3][c];
      float si_ = inp[0] + inp[1] + inp[2] + lnp[0] + lnp[1] + lnp[2];
      float sb = bnp[0] + bnp[1] + bnp[2];
      float2 ab = ab_from(s1, s2, s1, s2, 1024.f, 1.f, si_, sb, bnw[c], bnb[c], p1p[0]);
      AB[c] = ab.x; AB[3 + c] = ab.y;
    }
    __syncthreads();
  }
  {
    float P2a = p2p[0];
    for (int t = tid; t < 3072; t += 256) {
      int c = t >> 10, p = t & 1023;
      int oy = p >> 5, ox = p & 31;
      int si = ((oy * 12) >> 5) * 12 + ((ox * 12) >> 5);
      buf1[t] = AB[c] * ys0[c * 144 + si] + AB[3 + c] + P2a * u20[c * 144 + si];
    }
  }
  __syncthreads();
  // ---- conv1: (3,32,32) -> S=28, r=64 ----
  {
    const float* w1 = cw + 225;
    const float* w2 = c2w + 225;
    float sc[3] = {0, 0, 0}, sq[3] = {0, 0, 0};
    for (int p = tid; p < 784; p += 256) {
      int py = p / 28, px = p - py * 28;
      float a1[3], a2[3];
      #pragma unroll
      for (int c = 0; c < 3; ++c) { a1[c] = cb[3 + c]; a2[c] = c2b[3 + c]; }
      for (int ci = 0; ci < 3; ++ci) {
        #pragma unroll
        for (int ky = 0; ky < 5; ++ky) {
          const float* row = &buf1[ci * 1024 + (py + ky) * 32 + px];
          #pragma unroll
          for (int c = 0; c < 3; ++c) {
            #pragma unroll
            for (int kx = 0; kx < 5; ++kx) {
              a1[c] = fmaf(row[kx], w1[c * 75 + ci * 25 + ky * 5 + kx], a1[c]);
              a2[c] = fmaf(row[kx], w2[c * 75 + ci * 25 + ky * 5 + kx], a2[c]);
            }
          }
        }
      }
      int wy = ((py + 1) * 64 + 27) / 28 - (py * 64 + 27) / 28;
      int wx = ((px + 1) * 64 + 27) / 28 - (px * 64 + 27) / 28;
      float wgt = (float)(wy * wx);
      #pragma unroll
      for (int c = 0; c < 3; ++c) {
        ys1[c * 784 + p] = a1[c];
        u21[c * 784 + p] = a2[c];
        sc[c] += a1[c] * wgt;
        sq[c] += a1[c] * a1[c] * wgt;
      }
    }
    #pragma unroll
    for (int off = 32; off; off >>= 1) {
      #pragma unroll
      for (int c = 0; c < 3; ++c) {
        sc[c] += __shfl_down(sc[c], off);
        sq[c] += __shfl_down(sq[c], off);
      }
    }
    int wid = tid >> 6, lane = tid & 63;
    __syncthreads();  // protect redS reuse
    if (lane == 0) {
      #pragma unroll
      for (int c = 0; c < 3; ++c) { redS[wid][c] = sc[c]; redQ[wid][c] = sq[c]; }
    }
    __syncthreads();
    if (tid < 3) {
      int c = tid;
      float s1 = redS[0][c] + redS[1][c] + redS[2][c] + redS[3][c];
      float s2 = redQ[0][c] + redQ[1][c] + redQ[2][c] + redQ[3][c];
      float si_ = inp[3] + inp[4] + inp[5] + lnp[3] + lnp[4] + lnp[5];
      float sb = bnp[3] + bnp[4] + bnp[5];
      float2 ab = ab_from(s1, s2, s1, s2, 4096.f, 1.f, si_, sb, bnw[3 + c], bnb[3 + c], p1p[1]);
      AB[c] = ab.x; AB[3 + c] = ab.y;
    }
    __syncthreads();
  }
  {
    float P2b = p2p[1];
    for (int t = tid; t < 12288; t += 256) {
      int c = t >> 12, p = t & 4095;
      int oy = p >> 6, ox = p & 63;
      int si = ((oy * 28) >> 6) * 28 + ((ox * 28) >> 6);
      nb0[t] = AB[c] * ys1[c * 784 + si] + AB[3 + c] + P2b * u21[c * 784 + si];
    }
  }
}

// ---- attention HW=1024, pass 1 (fused y2+QKV recompute) ----
__global__ __launch_bounds__(256) void attn_rows_f(
    const float2* __restrict__ yu, const float* __restrict__ sums,
    const float* __restrict__ inp, const float* __restrict__ lnp,
    const float* __restrict__ bnp, const float* __restrict__ bnw,
    const float* __restrict__ bnb, const float* __restrict__ p1p,
    const float* __restrict__ p2p,
    const float* __restrict__ qw, const float* __restrict__ qb,
    const float* __restrict__ kw, const float* __restrict__ kb,
    float* __restrict__ Mp, float* __restrict__ Lp, int S,
    int pNT, int pT) {
  __shared__ float pA[3], pB[3], pP2v, sred[12];
  __shared__ __align__(16) float y2s[768], qs[768];
  int bid = blockIdx.x;
  int np = bid & 3; bid >>= 2;
  int mc = bid & 3;
  int b = bid >> 2;
  compute_AB_P(sums, b, pNT, pT, 1024.f, 32.f, inp, lnp, bnp, bnw, bnb, p1p,
               p2p, pA, pB, &pP2v, sred);
  size_t ybase = (size_t)b * 3 * S * S;
  for (int t = threadIdx.x; t < 768; t += 256) {
    int c = t >> 8, j = t & 255;
    int n = (np << 8) + j;
    int oy = n >> 5, ox = n & 31;
    int si = ((oy * S) >> 5) * S + ((ox * S) >> 5);
    float2 v = yu[ybase + c * S * S + si];
    y2s[t] = pA[c] * v.x + pB[c] + pP2v * v.y;
  }
  __syncthreads();
  for (int t = threadIdx.x; t < 768; t += 256) {
    int o = t >> 8, j = t & 255;
    qs[t] = qb[o] + qw[o * 3] * y2s[j] + qw[o * 3 + 1] * y2s[256 + j] +
            qw[o * 3 + 2] * y2s[512 + j];
  }
  __syncthreads();
  int m = (mc << 8) + threadIdx.x;
  int oy = m >> 5, ox = m & 31;
  int si = ((oy * S) >> 5) * S + ((ox * S) >> 5);
  float ym[3];
  #pragma unroll
  for (int c = 0; c < 3; ++c) {
    float2 v = yu[ybase + c * S * S + si];
    ym[c] = pA[c] * v.x + pB[c] + pP2v * v.y;
  }
  float k0 = (kb[0] + kw[0] * ym[0] + kw[1] * ym[1] + kw[2] * ym[2]) * LOG2E;
  float k1 = (kb[1] + kw[3] * ym[0] + kw[4] * ym[1] + kw[5] * ym[2]) * LOG2E;
  float k2 = (kb[2] + kw[6] * ym[0] + kw[7] * ym[1] + kw[8] * ym[2]) * LOG2E;
  const float4* qa4 = reinterpret_cast<const float4*>(qs);
  const float4* qb4 = reinterpret_cast<const float4*>(qs + 256);
  const float4* qc4 = reinterpret_cast<const float4*>(qs + 512);
  float mr = -1e30f;
  #pragma unroll 4
  for (int j = 0; j < 64; ++j) {
    float4 qa = qa4[j], qbv = qb4[j], qc = qc4[j];
    float s0 = k0 * qa.x + k1 * qbv.x + k2 * qc.x;
    float s1 = k0 * qa.y + k1 * qbv.y + k2 * qc.y;
    float s2 = k0 * qa.z + k1 * qbv.z + k2 * qc.z;
    float s3 = k0 * qa.w + k1 * qbv.w + k2 * qc.w;
    mr = fmaxf(mr, fmaxf(fmaxf(s0, s1), fmaxf(s2, s3)));
  }
  float l = 0.f;
  #pragma unroll 4
  for (int j = 0; j < 64; ++j) {
    float4 qa = qa4[j], qbv = qb4[j], qc = qc4[j];
    float s0 = k0 * qa.x + k1 * qbv.x + k2 * qc.x;
    float s1 = k0 * qa.y + k1 * qbv.y + k2 * qc.y;
    float s2 = k0 * qa.z + k1 * qbv.z + k2 * qc.z;
    float s3 = k0 * qa.w + k1 * qbv.w + k2 * qc.w;
    l += exp2f(s0 - mr) + exp2f(s1 - mr) + exp2f(s2 - mr) + exp2f(s3 - mr);
  }
  int idx = (b * 4 + np) * 1024 + m;
  Mp[idx] = mr;
  Lp[idx] = l;
}

// ---- attention HW=1024, pass 2: partial buffers, NO atomics ----
__global__ __launch_bounds__(256) void attn_out_f(
    const float2* __restrict__ yu, const float* __restrict__ sums,
    const float* __restrict__ inp, const float* __restrict__ lnp,
    const float* __restrict__ bnp, const float* __restrict__ bnw,
    const float* __restrict__ bnb, const float* __restrict__ p1p,
    const float* __restrict__ p2p,
    const float* __restrict__ qw, const float* __restrict__ qb,
    const float* __restrict__ kw, const float* __restrict__ kb,
    const float* __restrict__ vw, const float* __restrict__ vb,
    const float* __restrict__ Mp, const float* __restrict__ Lp,
    float* __restrict__ aout, int S, int pNT, int pT) {
  __shared__ float pA[3], pB[3], pP2v, sred[12];
  __shared__ __align__(16) float ym[768], ks[768], vs[768], Ms[256], Ls[256];
  int bid = blockIdx.x;
  int mp = bid & 3; bid >>= 2;
  int nc = bid & 3;
  int b = bid >> 2;
  compute_AB_P(sums, b, pNT, pT, 1024.f, 32.f, inp, lnp, bnp, bnw, bnb, p1p,
               p2p, pA, pB, &pP2v, sred);
  size_t ybase = (size_t)b * 3 * S * S;
  for (int t = threadIdx.x; t < 768; t += 256) {
    int c = t >> 8, j = t & 255;
    int m = (mp << 8) + j;
    int oy = m >> 5, ox = m & 31;
    int si = ((oy * S) >> 5) * S + ((ox * S) >> 5);
    float2 v = yu[ybase + c * S * S + si];
    ym[t] = pA[c] * v.x + pB[c] + pP2v * v.y;
  }
  __syncthreads();
  for (int t = threadIdx.x; t < 768; t += 256) {
    int o = t >> 8, j = t & 255;
    float y0 = ym[j], y1 = ym[256 + j], y2v = ym[512 + j];
    ks[t] = (kb[o] + kw[o * 3] * y0 + kw[o * 3 + 1] * y1 + kw[o * 3 + 2] * y2v) * LOG2E;
    vs[t] = vb[o] + vw[o * 3] * y0 + vw[o * 3 + 1] * y1 + vw[o * 3 + 2] * y2v;
  }
  {
    int t = threadIdx.x;
    int m = (mp << 8) + t;
    float M0 = Mp[(b * 4 + 0) * 1024 + m], M1 = Mp[(b * 4 + 1) * 1024 + m];
    float M2 = Mp[(b * 4 + 2) * 1024 + m], M3 = Mp[(b * 4 + 3) * 1024 + m];
    float L0 = Lp[(b * 4 + 0) * 1024 + m], L1 = Lp[(b * 4 + 1) * 1024 + m];
    float L2 = Lp[(b * 4 + 2) * 1024 + m], L3 = Lp[(b * 4 + 3) * 1024 + m];
    float MM = fmaxf(fmaxf(M0, M1), fmaxf(M2, M3));
    float LL = L0 * exp2f(M0 - MM) + L1 * exp2f(M1 - MM) +
               L2 * exp2f(M2 - MM) + L3 * exp2f(M3 - MM);
    Ms[t] = MM;
    Ls[t] = 1.0f / LL;
  }
  __syncthreads();
  int n = (nc << 8) + threadIdx.x;
  int oy = n >> 5, ox = n & 31;
  int si = ((oy * S) >> 5) * S + ((ox * S) >> 5);
  float yn[3];
  #pragma unroll
  for (int c = 0; c < 3; ++c) {
    float2 v = yu[ybase + c * S * S + si];
    yn[c] = pA[c] * v.x + pB[c] + pP2v * v.y;
  }
  float q0 = qb[0] + qw[0] * yn[0] + qw[1] * yn[1] + qw[2] * yn[2];
  float q1 = qb[1] + qw[3] * yn[0] + qw[4] * yn[1] + qw[5] * yn[2];
  float q2 = qb[2] + qw[6] * yn[0] + qw[7] * yn[1] + qw[8] * yn[2];
  float a0 = 0.f, a1 = 0.f, a2 = 0.f;
  const float4* ka4 = reinterpret_cast<const float4*>(ks);
  const float4* kb4 = reinterpret_cast<const float4*>(ks + 256);
  const float4* kc4 = reinterpret_cast<const float4*>(ks + 512);
  const float4* va4 = reinterpret_cast<const float4*>(vs);
  const float4* vb4 = reinterpret_cast<const float4*>(vs + 256);
  const float4* vc4 = reinterpret_cast<const float4*>(vs + 512);
  const float4* mm4 = reinterpret_cast<const float4*>(Ms);
  const float4* ll4 = reinterpret_cast<const float4*>(Ls);
  #pragma unroll 2
  for (int j = 0; j < 64; ++j) {
    float4 ka = ka4[j], kbv = kb4[j], kc = kc4[j];
    float4 va = va4[j], vbv = vb4[j], vc = vc4[j];
    float4 mm = mm4[j], ll = ll4[j];
    float s, w;
    s = ka.x * q0 + kbv.x * q1 + kc.x * q2;
    w = exp2f(s - mm.x) * ll.x;
    a0 = fmaf(va.x, w, a0); a1 = fmaf(vbv.x, w, a1); a2 = fmaf(vc.x, w, a2);
    s = ka.y * q0 + kbv.y * q1 + kc.y * q2;
    w = exp2f(s - mm.y) * ll.y;
    a0 = fmaf(va.y, w, a0); a1 = fmaf(vbv.y, w, a1); a2 = fmaf(vc.y, w, a2);
    s = ka.z * q0 + kbv.z * q1 + kc.z * q2;
    w = exp2f(s - mm.z) * ll.z;
    a0 = fmaf(va.z, w, a0); a1 = fmaf(vbv.z, w, a1); a2 = fmaf(vc.z, w, a2);
    s = ka.w * q0 + kbv.w * q1 + kc.w * q2;
    w = exp2f(s - mm.w) * ll.w;
    a0 = fmaf(va.w, w, a0); a1 = fmaf(vbv.w, w, a1); a2 = fmaf(vc.w, w, a2);
  }
  if (mp == 0) { a0 += yn[0]; a1 += yn[1]; a2 += yn[2]; }
  size_t o0 = (size_t)mp * 98304 + (size_t)b * 3072 + n;
  aout[o0] = a0;
  aout[o0 + 1024] = a1;
  aout[o0 + 2048] = a2;
}

// ---- attention HW=256 + following conv, 1024 threads, 4-way split loops ----
__global__ __launch_bounds__(1024) void attn256_conv(
    const float2* __restrict__ yu, const float* __restrict__ sums,
    const float* __restrict__ inp, const float* __restrict__ lnp,
    const float* __restrict__ bnp, const float* __restrict__ bnw,
    const float* __restrict__ bnb, const float* __restrict__ p1p,
    const float* __restrict__ p2p,
    const float* __restrict__ qw, const float* __restrict__ qb,
    const float* __restrict__ kw, const float* __restrict__ kb,
    const float* __restrict__ vw, const float* __restrict__ vb,
    const float* __restrict__ cw1, const float* __restrict__ cb1,
    const float* __restrict__ cw2, const float* __restrict__ cb2,
    float2* __restrict__ yu_out, float* __restrict__ sums_out, int S, int r,
    int pNT, int pT) {
  __shared__ float pA[3], pB[3], pP2v, sred[12];
  __shared__ __align__(16) float y2s[768], qs[768], ks[768], vs[768];
  __shared__ __align__(16) float Ms[256], Ls[256];
  __shared__ float Mq[1024], Lq[1024];
  __shared__ float Oq[3072];
  __shared__ float redS[16][3], redQ[16][3];
  int tid = threadIdx.x;
  int quarter = tid >> 8;
  int lane256 = tid & 255;
  int b = blockIdx.x;
  compute_AB_P(sums, b, pNT, pT, 256.f, 32.f, inp, lnp, bnp, bnw, bnb, p1p,
               p2p, pA, pB, &pP2v, sred);
  size_t ybase = (size_t)b * 3 * S * S;
  if (tid < 768) {
    int c = tid >> 8, p = tid & 255;
    int oy = p >> 4, ox = p & 15;
    int si = ((oy * S) >> 4) * S + ((ox * S) >> 4);
    float2 v = yu[ybase + c * S * S + si];
    y2s[tid] = pA[c] * v.x + pB[c] + pP2v * v.y;
  }
  __syncthreads();
  if (tid < 768) {
    int o = tid >> 8, p = tid & 255;
    float y0 = y2s[p], y1 = y2s[256 + p], y2v = y2s[512 + p];
    qs[tid] = qb[o] + qw[o * 3] * y0 + qw[o * 3 + 1] * y1 + qw[o * 3 + 2] * y2v;
    ks[tid] = (kb[o] + kw[o * 3] * y0 + kw[o * 3 + 1] * y1 + kw[o * 3 + 2] * y2v) * LOG2E;
    vs[tid] = vb[o] + vw[o * 3] * y0 + vw[o * 3 + 1] * y1 + vw[o * 3 + 2] * y2v;
  }
  __syncthreads();
  {
    int m = lane256;
    float kx = ks[m], ky = ks[256 + m], kz = ks[512 + m];
    int n0 = quarter << 6;
    const float4* qa4 = reinterpret_cast<const float4*>(qs + n0);
    const float4* qb4 = reinterpret_cast<const float4*>(qs + 256 + n0);
    const float4* qc4 = reinterpret_cast<const float4*>(qs + 512 + n0);
    float mr = -1e30f;
    #pragma unroll 4
    for (int j = 0; j < 16; ++j) {
      float4 qa = qa4[j], qbv = qb4[j], qc = qc4[j];
      float s0 = kx * qa.x + ky * qbv.x + kz * qc.x;
      float s1 = kx * qa.y + ky * qbv.y + kz * qc.y;
      float s2 = kx * qa.z + ky * qbv.z + kz * qc.z;
      float s3 = kx * qa.w + ky * qbv.w + kz * qc.w;
      mr = fmaxf(mr, fmaxf(fmaxf(s0, s1), fmaxf(s2, s3)));
    }
    float l = 0.f;
    #pragma unroll 4
    for (int j = 0; j < 16; ++j) {
      float4 qa = qa4[j], qbv = qb4[j], qc = qc4[j];
      float s0 = kx * qa.x + ky * qbv.x + kz * qc.x;
      float s1 = kx * qa.y + ky * qbv.y + kz * qc.y;
      float s2 = kx * qa.z + ky * qbv.z + kz * qc.z;
      float s3 = kx * qa.w + ky * qbv.w + kz * qc.w;
      l += exp2f(s0 - mr) + exp2f(s1 - mr) + exp2f(s2 - mr) + exp2f(s3 - mr);
    }
    Mq[tid] = mr;
    Lq[tid] = l;
  }
  __syncthreads();
  if (tid < 256) {
    float M0 = Mq[tid], M1 = Mq[256 + tid], M2 = Mq[512 + tid], M3 = Mq[768 + tid];
    float L0 = Lq[tid], L1 = Lq[256 + tid], L2 = Lq[512 + tid], L3 = Lq[768 + tid];
    float MM = fmaxf(fmaxf(M0, M1), fmaxf(M2, M3));
    float LL = L0 * exp2f(M0 - MM) + L1 * exp2f(M1 - MM) +
               L2 * exp2f(M2 - MM) + L3 * exp2f(M3 - MM);
    Ms[tid] = MM;
    Ls[tid] = 1.0f / LL;
  }
  __syncthreads();
  {
    int n = lane256;
    float q0 = qs[n], q1 = qs[256 + n], q2 = qs[512 + n];
    int m0 = quarter << 6;
    const float4* ka4 = reinterpret_cast<const float4*>(ks + m0);
    const float4* kb4 = reinterpret_cast<const float4*>(ks + 256 + m0);
    const float4* kc4 = reinterpret_cast<const float4*>(ks + 512 + m0);
    const float4* va4 = reinterpret_cast<const float4*>(vs + m0);
    const float4* vb4 = reinterpret_cast<const float4*>(vs + 256 + m0);
    const float4* vc4 = reinterpret_cast<const float4*>(vs + 512 + m0);
    const float4* mm4 = reinterpret_cast<const float4*>(Ms + m0);
    const float4* ll4 = reinterpret_cast<const float4*>(Ls + m0);
    float a0 = 0.f, a1 = 0.f, a2 = 0.f;
    #pragma unroll 4
    for (int j = 0; j < 16; ++j) {
      float4 ka = ka4[j], kbv = kb4[j], kc = kc4[j];
      float4 va = va4[j], vbv = vb4[j], vc = vc4[j];
      float4 mm = mm4[j], ll = ll4[j];
      float s, w;
      s = ka.x * q0 + kbv.x * q1 + kc.x * q2;
      w = exp2f(s - mm.x) * ll.x;
      a0 = fmaf(va.x, w, a0); a1 = fmaf(vbv.x, w, a1); a2 = fmaf(vc.x, w, a2);
      s = ka.y * q0 + kbv.y * q1 + kc.y * q2;
      w = exp2f(s - mm.y) * ll.y;
      a0 = fmaf(va.y, w, a0); a1 = fmaf(vbv.y, w, a1); a2 = fmaf(vc.y, w, a2);
      s = ka.z * q0 + kbv.z * q1 + kc.z * q2;
      w = exp2f(s - mm.z) * ll.z;
      a0 = fmaf(va.z, w, a0); a1 = fmaf(vbv.z, w, a1); a2 = fmaf(vc.z, w, a2);
      s = ka.w * q0 + kbv.w * q1 + kc.w * q2;
      w = exp2f(s - mm.w) * ll.w;
      a0 = fmaf(va.w, w, a0); a1 = fmaf(vbv.w, w, a1); a2 = fmaf(vc.w, w, a2);
    }
    Oq[tid] = a0;
    Oq[1024 + tid] = a1;
    Oq[2048 + tid] = a2;
  }
  __syncthreads();
  if (tid < 768) {
    int c = tid >> 8, n = tid & 255;
    int cb_ = c << 10;
    y2s[tid] += Oq[cb_ + n] + Oq[cb_ + 256 + n] + Oq[cb_ + 512 + n] + Oq[cb_ + 768 + n];
  }
  __syncthreads();
  float sc[3] = {0.f, 0.f, 0.f}, sq[3] = {0.f, 0.f, 0.f};
  int p = tid;
  if (p < 144) {
    int py = p / 12, px = p - py * 12;
    float a1[3], a2[3];
    #pragma unroll
    for (int c = 0; c < 3; ++c) { a1[c] = cb1[c]; a2[c] = cb2[c]; }
    #pragma unroll
    for (int ci = 0; ci < 3; ++ci) {
      #pragma unroll
      for (int ky = 0; ky < 5; ++ky) {
        const float* row = &y2s[ci * 256 + (py + ky) * 16 + px];
        #pragma unroll
        for (int c = 0; c < 3; ++c) {
          #pragma unroll
          for (int kx = 0; kx < 5; ++kx) {
            a1[c] = fmaf(row[kx], cw1[c * 75 + ci * 25 + ky * 5 + kx], a1[c]);
            a2[c] = fmaf(row[kx], cw2[c * 75 + ci * 25 + ky * 5 + kx], a2[c]);
          }
        }
      }
    }
    float wy = (float)(((py + 1) * r + 11) / 12 - (py * r + 11) / 12);
    float wx = (float)(((px + 1) * r + 11) / 12 - (px * r + 11) / 12);
    float wgt = wy * wx;
    #pragma unroll
    for (int c = 0; c < 3; ++c) {
      yu_out[(size_t)(b * 3 + c) * 144 + p] = make_float2(a1[c], a2[c]);
      sc[c] += a1[c] * wgt;
      sq[c] += a1[c] * a1[c] * wgt;
    }
  }
  #pragma unroll
  for (int off = 32; off; off >>= 1) {
    #pragma unroll
    for (int c = 0; c < 3; ++c) {
      sc[c] += __shfl_down(sc[c], off);
      sq[c] += __shfl_down(sq[c], off);
    }
  }
  int wid = tid >> 6, lane = tid & 63;
  if (lane == 0) {
    #pragma unroll
    for (int c = 0; c < 3; ++c) { redS[wid][c] = sc[c]; redQ[wid][c] = sq[c]; }
  }
  __syncthreads();
  if (tid < 3) {
    int c = tid;
    float s1 = 0.f, s2 = 0.f;
    #pragma unroll
    for (int w = 0; w < 16; ++w) { s1 += redS[w][c]; s2 += redQ[w][c]; }
    int NTg = (int)gridDim.x;  // 32, one block per image -> plain store
    sums_out[(2 * c) * NTg + b] = s1;
    sums_out[(2 * c + 1) * NTg + b] = s2;
  }
}

// ---- attn8 (rank-144) + conv9 fused; 1024 threads, 4-lane quad per row ----
__global__ __launch_bounds__(1024) void attn144c9_k(
    const float2* __restrict__ yin, const float* __restrict__ sums,
    const float* __restrict__ inp, const float* __restrict__ lnp,
    const float* __restrict__ bnp, const float* __restrict__ bnw,
    const float* __restrict__ bnb, const float* __restrict__ p1p,
    const float* __restrict__ p2p,
    const float* __restrict__ qw, const float* __restrict__ qb,
    const float* __restrict__ kw, const float* __restrict__ kb,
    const float* __restrict__ vw, const float* __restrict__ vb,
    const float* __restrict__ cw1, const float* __restrict__ cb1,
    const float* __restrict__ cw2, const float* __restrict__ cb2,
    float2* __restrict__ yu_out, float* __restrict__ sums_out) {
  __shared__ float pA[3], pB[3], pP2v, sred[12];
  __shared__ float y2[432], Osh[432];
  __shared__ __align__(16) float4 qkp[144];  // (q0,q1,q2, wn)
  __shared__ __align__(16) float4 ksp[144];  // (k*log2e x3, M_row)
  __shared__ __align__(16) float4 vsp[144];  // (v0,v1,v2, wn/l)
  __shared__ float redS16[16][3], redQ16[16][3];
  int b = blockIdx.x;
  int t = threadIdx.x;
  compute_AB_P(sums, b, 32, 1, 1024.f, 32.f, inp, lnp, bnp, bnw, bnb, p1p,
               p2p, pA, pB, &pP2v, sred);
  if (t < 432) {
    int c = t / 144, j = t - c * 144;
    float2 v = yin[(size_t)(b * 3 + c) * 144 + j];
    y2[t] = pA[c] * v.x + pB[c] + pP2v * v.y;
  }
  __syncthreads();
  if (t < 144) {
    int j = t;
    float y0 = y2[j], y1 = y2[144 + j], y2v = y2[288 + j];
    int jy = j / 12, jx = j - jy * 12;
    int cy = (8 * (jy + 1) + 2) / 3 - (8 * jy + 2) / 3;
    int cx = (8 * (jx + 1) + 2) / 3 - (8 * jx + 2) / 3;
    float wnv = (float)(cy * cx);
    qkp[j] = make_float4(
        qb[0] + qw[0] * y0 + qw[1] * y1 + qw[2] * y2v,
        qb[1] + qw[3] * y0 + qw[4] * y1 + qw[5] * y2v,
        qb[2] + qw[6] * y0 + qw[7] * y1 + qw[8] * y2v, wnv);
    ksp[j] = make_float4(
        (kb[0] + kw[0] * y0 + kw[1] * y1 + kw[2] * y2v) * LOG2E,
        (kb[1] + kw[3] * y0 + kw[4] * y1 + kw[5] * y2v) * LOG2E,
        (kb[2] + kw[6] * y0 + kw[7] * y1 + kw[8] * y2v) * LOG2E, 0.f);
    vsp[j] = make_float4(
        vb[0] + vw[0] * y0 + vw[1] * y1 + vw[2] * y2v,
        vb[1] + vw[3] * y0 + vw[4] * y1 + vw[5] * y2v,
        vb[2] + vw[6] * y0 + vw[7] * y1 + vw[8] * y2v, 0.f);
  }
  __syncthreads();
  int m4 = t >> 2, part = t & 3;
  // M/L: quad (4 lanes) per row m4; each part reduces 36 of 144 terms.
  if (m4 < 144) {
    float4 kk = ksp[m4];
    int n0 = part * 36;
    float mr = -1e30f;
    #pragma unroll 4
    for (int nn = n0; nn < n0 + 36; ++nn) {
      float4 q4 = qkp[nn];
      float s = kk.x * q4.x + kk.y * q4.y + kk.z * q4.z;
      mr = fmaxf(mr, s);
    }
    mr = fmaxf(mr, __shfl_xor(mr, 1));
    mr = fmaxf(mr, __shfl_xor(mr, 2));
    float l = 0.f;
    #pragma unroll 4
    for (int nn = n0; nn < n0 + 36; ++nn) {
      float4 q4 = qkp[nn];
      float s = kk.x * q4.x + kk.y * q4.y + kk.z * q4.z;
      l += q4.w * exp2f(s - mr);
    }
    l += __shfl_xor(l, 1);
    l += __shfl_xor(l, 2);
    if (part == 0) {
      ksp[m4].w = mr;
      vsp[m4].w = qkp[m4].w / l;  // wn[m] / l[m]
    }
  }
  __syncthreads();
  // PV: quad per query row; each part sums 36 of 144 keys.
  if (m4 < 144) {
    int nq = m4;
    float4 q4 = qkp[nq];
    int m0 = part * 36;
    float a0 = 0.f, a1 = 0.f, a2 = 0.f;
    #pragma unroll 4
    for (int m = m0; m < m0 + 36; ++m) {
      float4 k4 = ksp[m];
      float4 v4 = vsp[m];
      float s = k4.x * q4.x + k4.y * q4.y + k4.z * q4.z;
      float w = exp2f(s - k4.w) * v4.w;
      a0 = fmaf(v4.x, w, a0);
      a1 = fmaf(v4.y, w, a1);
      a2 = fmaf(v4.z, w, a2);
    }
    a0 += __shfl_xor(a0, 1);
    a0 += __shfl_xor(a0, 2);
    a1 += __shfl_xor(a1, 1);
    a1 += __shfl_xor(a1, 2);
    a2 += __shfl_xor(a2, 1);
    a2 += __shfl_xor(a2, 2);
    if (part == 0) {
      Osh[nq] = a0 + y2[nq];
      Osh[144 + nq] = a1 + y2[144 + nq];
      Osh[288 + nq] = a2 + y2[288 + nq];
    }
  }
  __syncthreads();
  // conv9: 12-grid upsampled to 32, 5x5 valid -> 28x28, r=64; 1 output/thread
  float sc[3] = {0.f, 0.f, 0.f}, sq[3] = {0.f, 0.f, 0.f};
  if (t < 784) {
    int py = t / 28, px = t - py * 28;
    float a1[3], a2[3];
    #pragma unroll
    for (int c = 0; c < 3; ++c) { a1[c] = cb1[c]; a2[c] = cb2[c]; }
    #pragma unroll
    for (int ci = 0; ci < 3; ++ci) {
      const float* obase = &Osh[ci * 144];
      #pragma unroll
      for (int ky = 0; ky < 5; ++ky) {
        int sy = ((py + ky) * 12) >> 5;
        const float* orow = obase + sy * 12;
        #pragma unroll
        for (int kx = 0; kx < 5; ++kx) {
          int sx = ((px + kx) * 12) >> 5;
          float v = orow[sx];
          #pragma unroll
          for (int c = 0; c < 3; ++c) {
            a1[c] = fmaf(v, cw1[c * 75 + ci * 25 + ky * 5 + kx], a1[c]);
            a2[c] = fmaf(v, cw2[c * 75 + ci * 25 + ky * 5 + kx], a2[c]);
          }
        }
      }
    }
    float wy = (float)(((py + 1) * 64 + 27) / 28 - (py * 64 + 27) / 28);
    float wx = (float)(((px + 1) * 64 + 27) / 28 - (px * 64 + 27) / 28);
    float wgt = wy * wx;
    #pragma unroll
    for (int c = 0; c < 3; ++c) {
      yu_out[((size_t)(b * 3 + c) * 28 + py) * 28 + px] = make_float2(a1[c], a2[c]);
      sc[c] += a1[c] * wgt;
      sq[c] += a1[c] * a1[c] * wgt;
    }
  }
  // 16-wave stats reduce, plain store
  #pragma unroll
  for (int off = 32; off; off >>= 1) {
    #pragma unroll
    for (int c = 0; c < 3; ++c) {
      sc[c] += __shfl_down(sc[c], off);
      sq[c] += __shfl_down(sq[c], off);
    }
  }
  int wid = t >> 6, lane = t & 63;
  if (lane == 0) {
    #pragma unroll
    for (int c = 0; c < 3; ++c) { redS16[wid][c] = sc[c]; redQ16[wid][c] = sq[c]; }
  }
  __syncthreads();
  if (t < 3) {
    int c = t;
    float s1 = 0.f, s2 = 0.f;
    #pragma unroll
    for (int w = 0; w < 16; ++w) { s1 += redS16[w][c]; s2 += redQ16[w][c]; }
    sums_out[(2 * c) * 32 + b] = s1;
    sums_out[(2 * c + 1) * 32 + b] = s2;
  }
}

// ---- final: affine + p2*u2 + tanh -> out; 2048 blocks, float4 stores ----
__global__ __launch_bounds__(256) void elem_final(
    const float2* __restrict__ yu, const float* __restrict__ sums,
    const float* __restrict__ inp, const float* __restrict__ lnp,
    const float* __restrict__ bnp, const float* __restrict__ bnw,
    const float* __restrict__ bnb, const float* __restrict__ p1p,
    const float* __restrict__ p2p, float* __restrict__ out, int S,
    int pNT, int pT) {
  __shared__ float pA[3], pB[3], pP2v, sred[12];
  int bid = xcd_swz();
  int n = bid >> 6;
  int part = bid & 63;
  compute_AB_P(sums, n, pNT, pT, 65536.f, 32.f, inp, lnp, bnp, bnw, bnb, p1p,
               p2p, pA, pB, &pP2v, sred);
  int p0 = (part << 10) + ((int)threadIdx.x << 2);
  int oy = p0 >> 8;
  int oxb = p0 & 255;
  int sy = ((oy * S) >> 8) * S;
  int si0 = sy + ((oxb * S) >> 8);
  int si1 = sy + (((oxb + 1) * S) >> 8);
  int si2 = sy + (((oxb + 2) * S) >> 8);
  int si3 = sy + (((oxb + 3) * S) >> 8);
  size_t ybase = (size_t)n * 3 * S * S;
  #pragma unroll
  for (int c = 0; c < 3; ++c) {
    const float2* yp = yu + ybase + (size_t)c * S * S;
    float2 v0 = yp[si0], v1 = yp[si1], v2 = yp[si2], v3 = yp[si3];
    float4 r;
    r.x = tanhf(pA[c] * v0.x + pB[c] + pP2v * v0.y);
    r.y = tanhf(pA[c] * v1.x + pB[c] + pP2v * v1.y);
    r.z = tanhf(pA[c] * v2.x + pB[c] + pP2v * v2.y);
    r.w = tanhf(pA[c] * v3.x + pB[c] + pP2v * v3.y);
    *reinterpret_cast<float4*>(&out[((size_t)(n * 3 + c) << 16) + p0]) = r;
  }
}

#define NPX nullptr, nullptr, nullptr, nullptr, nullptr, nullptr, nullptr, \
            nullptr, nullptr, 0, 0, 0, 0, 0

extern "C" void kernel_launch(void* const* d_in, const int* in_sizes, int n_in,
                              void* d_out, int out_size, void* d_ws, size_t ws_size,
                              hipStream_t stream) {
  const float* x       = (const float*)d_in[0];
  const float* noise_z = (const float*)d_in[1];
  const float* lin_w   = (const float*)d_in[2];
  const float* lin_b   = (const float*)d_in[3];
  const float* conv_w  = (const float*)d_in[4];
  const float* conv_b  = (const float*)d_in[5];
  const float* conv2_w = (const float*)d_in[6];
  const float* conv2_b = (const float*)d_in[7];
  const float* q_w     = (const float*)d_in[8];
  const float* q_b     = (const float*)d_in[9];
  const float* k_w     = (const float*)d_in[10];
  const float* k_b     = (const float*)d_in[11];
  const float* v_w     = (const float*)d_in[12];
  const float* v_b     = (const float*)d_in[13];
  const float* in_p    = (const float*)d_in[14];
  const float* ln_p    = (const float*)d_in[15];
  const float* bn_p    = (const float*)d_in[16];
  const float* bn_w    = (const float*)d_in[17];
  const float* bn_b    = (const float*)d_in[18];
  const float* p1      = (const float*)d_in[19];
  const float* p2      = (const float*)d_in[20];
  float* out = (float*)d_out;

  float* ws = (float*)d_ws;
  size_t off = 0;
  auto alloc = [&](size_t nf) { float* p = ws + off; off += nf; return p; };
  // per-stage partial stats, planar [6][NT]; NT = producer grid size
  float* PS    = alloc(27264);
  float* PS2   = PS;            // conv2:  NT=1024
  float* PS3   = PS + 6144;     // conv3:  NT=2048
  float* PS4   = PS + 18432;    // conv4:  NT=512
  float* PS5   = PS + 21504;    // conv5:  NT=128
  float* PS6   = PS + 22272;    // conv6:  NT=64
  float* PS6a  = PS + 22656;    // attn6:  NT=32
  float* PS7a  = PS + 22848;    // attn7:  NT=32
  float* PS9   = PS + 23040;    // attn144c9: NT=32
  float* PS10  = PS + 23424;    // conv10: NT=128
  float* PS11  = PS + 24192;    // conv11: NT=512
  float* P45  = alloc(393216);
  float2* YU2 = (float2*)alloc(12192768);
  float2* PA  = (float2*)alloc(3145728);
  float2* PB  = (float2*)alloc(3145728);
  float* Mp   = alloc(131072);
  float* Lp   = alloc(131072);
  float* NB0  = alloc(12288);
  float* LIN  = alloc(768);

  const float* nul = nullptr;
  const float2* nul2 = nullptr;

  linear_wave<<<192, 256, 0, stream>>>(noise_z, lin_w, lin_b, LIN);
  noise_rest<<<1, 256, 0, stream>>>(LIN, conv_w, conv_b, conv2_w, conv2_b,
      in_p, ln_p, bn_p, bn_w, bn_b, p1, p2, NB0);

  // conv2: x -> YU2 (S=252, r=256), 64x32 tile, async global->LDS staging
  conv_up_t<0, 32><<<1024, 256, 0, stream>>>(x, nul2, YU2, conv_w + 450,
      conv_b + 6, conv2_w + 450, conv2_b + 6, PS2, 256, 252, 256, 4, 8,
      NPX);
  // conv3: fused(b2) YU2 -> PA (S=128), 32x8 tile; prev Sp=252, logrp=8
  conv_dn_t<1, false><<<2048, 256, 0, stream>>>(nul, YU2, PA,
      conv_w + 675, conv_b + 9, conv2_w + 675, conv2_b + 9, PS3,
      256, 128, 252, 7, 4, 16,
      PS2, in_p + 6, ln_p + 6, bn_p + 6, bn_w + 6, bn_b + 6, p1 + 2,
      p2 + 2, nul, 32, 252, 8, 1024, 32);
  // conv4: fused(b3) PA -> PB (S=64); prev identity
  conv_dn_t<1, true><<<512, 256, 0, stream>>>(nul, PA, PB,
      conv_w + 900, conv_b + 12, conv2_w + 900, conv2_b + 12, PS4,
      128, 64, 124, 6, 2, 8,
      PS3, in_p + 9, ln_p + 9, bn_p + 9, bn_w + 9, bn_b + 9, p1 + 3,
      p2 + 3, nul, 32, 128, 7, 2048, 64);
  // conv5: fused(b4)+noise PB -> PA (S=32); prev identity
  conv_dn_t<1, true><<<128, 256, 0, stream>>>(nul, PB, PA,
      conv_w + 1125, conv_b + 15, conv2_w + 1125, conv2_b + 15, PS5,
      64, 32, 60, 5, 1, 4,
      PS4, in_p + 12, ln_p + 12, bn_p + 12, bn_w + 12, bn_b + 12, p1 + 4,
      p2 + 4, NB0, 32, 64, 6, 512, 16);
  // attn5 (HW=1024) on PA (S=32) -> partials P45
  attn_rows_f<<<512, 256, 0, stream>>>(PA, PS5, in_p + 15, ln_p + 15,
      bn_p + 15, bn_w + 15, bn_b + 15, p1 + 5, p2 + 5,
      q_w + 45, q_b + 15, k_w + 45, k_b + 15, Mp, Lp, 32, 128, 4);
  attn_out_f<<<512, 256, 0, stream>>>(PA, PS5, in_p + 15, ln_p + 15,
      bn_p + 15, bn_w + 15, bn_b + 15, p1 + 5, p2 + 5,
      q_w + 45, q_b + 15, k_w + 45, k_b + 15, v_w + 45, v_b + 15, Mp, Lp, P45,
      32, 128, 4);
  // conv6: SUM4 staging from P45 -> PB (S=16)
  conv_dn_t<2, false><<<64, 256, 0, stream>>>(P45, nul2, PB,
      conv_w + 1350, conv_b + 18, conv2_w + 1350, conv2_b + 18, PS6,
      32, 16, 28, 4, 1, 2, NPX);
  // attn6 (HW=256) on PB (S=16) + conv7 (r=16) -> PA (S=12)
  attn256_conv<<<32, 1024, 0, stream>>>(PB, PS6, in_p + 18, ln_p + 18,
      bn_p + 18, bn_w + 18, bn_b + 18, p1 + 6, p2 + 6,
      q_w + 54, q_b + 18, k_w + 54, k_b + 18, v_w + 54, v_b + 18,
      conv_w + 1575, conv_b + 21, conv2_w + 1575, conv2_b + 21,
      PA, PS6a, 16, 16, 64, 2);
  // attn7 (HW=256) on PA (S=12) + conv8 (r=32) -> PB (S=12)
  attn256_conv<<<32, 1024, 0, stream>>>(PA, PS6a, in_p + 21, ln_p + 21,
      bn_p + 21, bn_w + 21, bn_b + 21, p1 + 7, p2 + 7,
      q_w + 63, q_b + 21, k_w + 63, k_b + 21, v_w + 63, v_b + 21,
      conv_w + 1800, conv_b + 24, conv2_w + 1800, conv2_b + 24,
      PB, PS7a, 12, 32, 32, 1);
  // attn8 (rank-144, quad-split) + conv9 fused: PB(144) -> PA (S=28, r=64)
  attn144c9_k<<<32, 1024, 0, stream>>>(PB, PS7a, in_p + 24, ln_p + 24,
      bn_p + 24, bn_w + 24, bn_b + 24, p1 + 8, p2 + 8,
      q_w + 72, q_b + 24, k_w + 72, k_b + 24, v_w + 72, v_b + 24,
      conv_w + 2025, conv_b + 27, conv2_w + 2025, conv2_b + 27,
      PA, PS9);
  // conv10: fused(b9) PA -> PB (S=60); prev Sp=28, logrp=6; stats NT=32,T=1
  conv_up_t<1, 16><<<128, 256, 0, stream>>>(nul, PA, PB, conv_w + 2250,
      conv_b + 30, conv2_w + 2250, conv2_b + 30, PS10, 64, 60, 128, 1, 4,
      PS9, in_p + 27, ln_p + 27, bn_p + 27, bn_w + 27, bn_b + 27,
      p1 + 9, p2 + 9, nul, 32, 28, 6, 32, 1);
  // conv11: fused(b10) PB -> YU2 (S=124); prev Sp=60, logrp=7
  conv_up_t<1, 16><<<512, 256, 0, stream>>>(nul, PB, YU2, conv_w + 2475,
      conv_b + 33, conv2_w + 2475, conv2_b + 33, PS11, 128, 124, 256, 2, 8,
      PS10, in_p + 30, ln_p + 30, bn_p + 30, bn_w + 30, bn_b + 30,
      p1 + 10, p2 + 10, nul, 32, 60, 7, 128, 4);
  // final: tanh -> out (2048 blocks, 4 px/thread, float4 stores)
  elem_final<<<2048, 256, 0, stream>>>(YU2, PS11, in_p + 33, ln_p + 33,
      bn_p + 33, bn_w + 33, bn_b + 33, p1 + 11, p2 + 11, out, 124, 512, 16);
}

// Round 12
// 393.966 us; speedup vs baseline: 1.0652x; 1.0321x over previous
//
#include <hip/hip_runtime.h>
#include <math.h>

#define EPS 1e-5f
#define LOG2E 1.44269504088896340736f

#define AS_GLOBAL __attribute__((address_space(1)))
#define AS_LDS    __attribute__((address_space(3)))

// ---- shared affine-fold helper: A,B from sums (instance+batch norm + p1) ----
__device__ __forceinline__ float2 ab_from(float s1, float s2, float bs, float bs2,
    float hw, float Nf, float si_, float sb, float bnw_c, float bnb_c, float p1v) {
  float inv = 1.0f / hw;
  float mi = s1 * inv, vi = s2 * inv - mi * mi;
  float ri = rsqrtf(vi + EPS);
  float invb = 1.0f / (Nf * hw);
  float mb = bs * invb, vb = bs2 * invb - mb * mb;
  float rb = rsqrtf(vb + EPS);
  float A = 1.0f + si_ * ri + sb * rb * bnw_c;
  float B = -(si_ * ri * mi + sb * rb * bnw_c * mb) + sb * bnb_c;
  return make_float2(A * p1v, B * p1v);
}

// Partial-stats layout: P[c2][NT] planar, c2 = 2*c (+1 for sumsq), NT = producer grid.
__device__ __forceinline__ void compute_AB_P(
    const float* __restrict__ P, int n, int NT, int T, float hw, float Nf,
    const float* __restrict__ inp, const float* __restrict__ lnp,
    const float* __restrict__ bnp, const float* __restrict__ bnw,
    const float* __restrict__ bnb, const float* __restrict__ p1p,
    const float* __restrict__ p2p, float* pA, float* pB, float* pP2,
    float* sred /* __shared__ float[12] */) {
  int t = threadIdx.x;
  if (t == 0) *pP2 = p2p[0];
  if (t < 192) {
    int c2 = t >> 5, l = t & 31;
    const float* pp = P + c2 * NT;
    float aAll = 0.f, aOwn = 0.f;
    int base = n * T;
    #pragma unroll 4
    for (int i = l; i < NT; i += 32) {
      float v = pp[i];
      aAll += v;
      if ((unsigned)(i - base) < (unsigned)T) aOwn += v;
    }
    #pragma unroll
    for (int off = 16; off; off >>= 1) {
      aAll += __shfl_down(aAll, off, 32);
      aOwn += __shfl_down(aOwn, off, 32);
    }
    if (l == 0) { sred[c2] = aOwn; sred[6 + c2] = aAll; }
  }
  __syncthreads();
  if (t < 3) {
    int c = t;
    float si_ = inp[0] + inp[1] + inp[2] + lnp[0] + lnp[1] + lnp[2];
    float sb = bnp[0] + bnp[1] + bnp[2];
    float2 ab = ab_from(sred[2 * c], sred[2 * c + 1], sred[6 + 2 * c],
                        sred[6 + 2 * c + 1], hw, Nf, si_, sb, bnw[c], bnb[c],
                        p1p[0]);
    pA[c] = ab.x;
    pB[c] = ab.y;
  }
  __syncthreads();
}

// stats block-reduce (256 threads, all must participate): plain store, NO atomics.
#define STATS_REDUCE_STORE(scv, sqv, sumsp, bidv)                             \
  {                                                                           \
    _Pragma("unroll")                                                         \
    for (int off = 32; off; off >>= 1) {                                      \
      _Pragma("unroll")                                                       \
      for (int c = 0; c < 3; ++c) {                                           \
        scv[c] += __shfl_down(scv[c], off);                                   \
        sqv[c] += __shfl_down(sqv[c], off);                                   \
      }                                                                       \
    }                                                                         \
    __shared__ float redS[4][3], redQ[4][3];                                  \
    int wid = threadIdx.x >> 6, lane = threadIdx.x & 63;                      \
    if (lane == 0) {                                                          \
      _Pragma("unroll")                                                       \
      for (int c = 0; c < 3; ++c) { redS[wid][c] = scv[c]; redQ[wid][c] = sqv[c]; } \
    }                                                                         \
    __syncthreads();                                                          \
    if (threadIdx.x < 3) {                                                    \
      int c = threadIdx.x;                                                    \
      int NTg = (int)gridDim.x;                                               \
      sumsp[(2 * c) * NTg + (bidv)] =                                         \
          redS[0][c] + redS[1][c] + redS[2][c] + redS[3][c];                  \
      sumsp[(2 * c + 1) * NTg + (bidv)] =                                     \
          redQ[0][c] + redQ[1][c] + redQ[2][c] + redQ[3][c];                  \
    }                                                                         \
  }

// XCD-aware bijective swizzle (grid must be a multiple of 8).
__device__ __forceinline__ int xcd_swz() {
  return ((int)(blockIdx.x & 7)) * ((int)gridDim.x >> 3) + ((int)blockIdx.x >> 3);
}

// ---- staging value loader ----
// MODE: 0=direct, 1=fused affine float2 (+noise), 2=sum4 partials, 3=gather small grid
template <int MODE, bool IDENT>
__device__ __forceinline__ float stage_val(
    const float* __restrict__ inb, size_t ps,
    const float2* __restrict__ pyu, size_t pbase,
    int Hin, int gy, int gx, int Sp, int logrp,
    const float* pA, const float* pB, float pP2v,
    const float* __restrict__ pnoise, int cc) {
  if (MODE == 1) {
    int gxs = IDENT ? gx : ((gx * Sp) >> logrp);
    int rbase = IDENT ? gy * Sp : ((gy * Sp) >> logrp) * Sp;
    float2 v = pyu[pbase + (size_t)cc * Sp * Sp + rbase + gxs];
    float val = pA[cc] * v.x + pB[cc] + pP2v * v.y;
    if (pnoise) val += pnoise[((size_t)cc * Hin + gy) * Hin + gx];
    return val;
  } else if (MODE == 2) {
    size_t idx = ((size_t)cc * Hin + gy) * Hin + gx;
    return inb[idx] + inb[idx + ps] + inb[idx + 2 * ps] + inb[idx + 3 * ps];
  } else if (MODE == 3) {
    int gys = (gy * Sp) >> logrp, gxs = (gx * Sp) >> logrp;
    return inb[(cc * Sp + gys) * Sp + gxs];
  } else {
    return inb[((size_t)cc * Hin + gy) * Hin + gx];
  }
}

// ---- division-free 2D staging of a 3 x IHv x 68 tile ----
template <int MODE, bool IDENT, int IHv>
__device__ __forceinline__ void stage_tile(
    float* __restrict__ lin, const float* __restrict__ inb, size_t ps,
    const float2* __restrict__ pyu, size_t pbase,
    int Hin, int sy0, int sx0, int Sp, int logrp,
    const float* pA, const float* pB, float pP2v,
    const float* __restrict__ pnoise) {
  const int IW = 68;
  int colt = threadIdx.x & 63;
  int r4 = threadIdx.x >> 6;
  int gx = sx0 + colt; gx = gx < Hin ? gx : Hin - 1;
  #pragma unroll
  for (int cc = 0; cc < 3; ++cc) {
    #pragma unroll
    for (int rb = 0; rb < IHv / 4; ++rb) {
      int rr = r4 + (rb << 2);
      int gy = sy0 + rr; gy = gy < Hin ? gy : Hin - 1;
      lin[(cc * IHv + rr) * IW + colt] =
          stage_val<MODE, IDENT>(inb, ps, pyu, pbase, Hin, gy, gx, Sp, logrp,
                                 pA, pB, pP2v, pnoise, cc);
    }
  }
  for (int t = threadIdx.x; t < 3 * IHv * 4; t += 256) {
    int col2 = 64 + (t & 3);
    int rowlin = t >> 2;
    int cc = rowlin / IHv, rr = rowlin - cc * IHv;
    int gx2 = sx0 + col2; gx2 = gx2 < Hin ? gx2 : Hin - 1;
    int gy = sy0 + rr; gy = gy < Hin ? gy : Hin - 1;
    lin[(cc * IHv + rr) * IW + col2] =
        stage_val<MODE, IDENT>(inb, ps, pyu, pbase, Hin, gy, gx2, Sp, logrp,
                               pA, pB, pP2v, pnoise, cc);
  }
}

// ---- LDS-tiled upsample conv (S==hc): 64 x THv tile, TX=4, float2 out ----
template <int SMODE, int THv>
__global__ __launch_bounds__(256) void conv_up_t(
    const float* __restrict__ in, const float2* __restrict__ pyu,
    float2* __restrict__ yu,
    const float* __restrict__ w1, const float* __restrict__ b1,
    const float* __restrict__ w2, const float* __restrict__ b2,
    float* __restrict__ sums, int Hin, int S, int r, int tilesX, int tilesY,
    const float* __restrict__ psums,
    const float* __restrict__ pinp, const float* __restrict__ plnp,
    const float* __restrict__ pbnp, const float* __restrict__ pbnw,
    const float* __restrict__ pbnb, const float* __restrict__ pp1,
    const float* __restrict__ pp2, const float* __restrict__ pnoise,
    int pN, int Sp, int logrp, int pNT, int pT) {
  const int TW = 64, IW = 68, IH = THv + 4, NH = THv / 16;
  __shared__ float lin[3 * IH * IW];
  __shared__ float pA[3], pB[3], pP2v, sred[12];
  int bid = xcd_swz();
  int tpi = tilesX * tilesY;
  int n = bid / tpi;
  int trem = bid - n * tpi;
  int tyB = trem / tilesX, txB = trem - tyB * tilesX;
  int px0 = txB * TW, py0 = tyB * THv;
  const float* inb = in + (size_t)n * 3 * Hin * Hin;
  if (SMODE == 1) {
    compute_AB_P(psums, n, pNT, pT, (float)(Hin * Hin), (float)pN, pinp, plnp,
                 pbnp, pbnw, pbnb, pp1, pp2, pA, pB, &pP2v, sred);
    size_t pbase = (size_t)n * 3 * Sp * Sp;
    stage_tile<1, false, IH>(lin, nullptr, 0, pyu, pbase, Hin, py0, px0, Sp,
                             logrp, pA, pB, pP2v, pnoise);
  } else if (SMODE == 3) {
    const float* smallb = in + (size_t)n * 3 * Sp * Sp;
    stage_tile<3, false, IH>(lin, smallb, 0, nullptr, 0, Hin, py0, px0, Sp,
                             logrp, nullptr, nullptr, 0.f, nullptr);
  } else {
    if (px0 + IW <= Hin && py0 + IH <= Hin) {
      for (int t4 = threadIdx.x; t4 < 3 * IH * 17; t4 += 256) {
        int cc = t4 / (IH * 17);
        int rem = t4 - cc * (IH * 17);
        int rr = rem / 17, j = rem - rr * 17;
        const float* src = inb + ((size_t)cc * Hin + py0 + rr) * Hin + px0 + 4 * j;
        int base = t4 - (threadIdx.x & 63);  // wave-uniform float4 index
        __builtin_amdgcn_global_load_lds(
            (const AS_GLOBAL void*)src,
            (AS_LDS void*)(lin + 4 * base), 16, 0, 0);
      }
    } else {
      stage_tile<0, false, IH>(lin, inb, 0, nullptr, 0, Hin, py0, px0, 0, 0,
                               nullptr, nullptr, 0.f, nullptr);
    }
  }
  __syncthreads();
  int tx = threadIdx.x & 15, ty = threadIdx.x >> 4;
  int lx0 = tx * 4;
  float a1[NH][3][4], a2[NH][3][4];
  #pragma unroll
  for (int h = 0; h < NH; ++h) {
    #pragma unroll
    for (int c = 0; c < 3; ++c) {
      float bb1 = b1[c], bb2 = b2[c];
      #pragma unroll
      for (int x = 0; x < 4; ++x) { a1[h][c][x] = bb1; a2[h][c][x] = bb2; }
    }
  }
  #pragma unroll 1
  for (int ci = 0; ci < 3; ++ci) {
    const float* wp1 = w1 + ci * 25;
    const float* wp2 = w2 + ci * 25;
    #pragma unroll
    for (int h = 0; h < NH; ++h) {
      const float* lrow = lin + (ci * IH + ty + 16 * h) * IW + lx0;
      float v[5][8];
      #pragma unroll
      for (int ky = 0; ky < 5; ++ky) {
        #pragma unroll
        for (int j = 0; j < 8; ++j) { v[ky][j] = lrow[ky * IW + j]; }
      }
      #pragma unroll
      for (int ky = 0; ky < 5; ++ky) {
        #pragma unroll
        for (int c = 0; c < 3; ++c) {
          #pragma unroll
          for (int kx = 0; kx < 5; ++kx) {
            float wa = wp1[c * 75 + ky * 5 + kx];
            float wb = wp2[c * 75 + ky * 5 + kx];
            #pragma unroll
            for (int x = 0; x < 4; ++x) {
              a1[h][c][x] = fmaf(v[ky][kx + x], wa, a1[h][c][x]);
              a2[h][c][x] = fmaf(v[ky][kx + x], wb, a2[h][c][x]);
            }
          }
        }
      }
    }
  }
  float sc[3] = {0.f, 0.f, 0.f}, sq[3] = {0.f, 0.f, 0.f};
  int hc = S;
  int px = px0 + lx0;
  #pragma unroll
  for (int h = 0; h < NH; ++h) {
    int py = py0 + ty + 16 * h;
    bool valid = (py < S) && (px < S);
    if (valid) {
      float wy = (float)(((py + 1) * r + hc - 1) / hc - (py * r + hc - 1) / hc);
      float wx[4];
      #pragma unroll
      for (int x = 0; x < 4; ++x) {
        int pxx = px + x;
        wx[x] = (float)(((pxx + 1) * r + hc - 1) / hc - (pxx * r + hc - 1) / hc);
      }
      #pragma unroll
      for (int c = 0; c < 3; ++c) {
        size_t idx = ((size_t)(n * 3 + c) * S + py) * S + px;
        float2* yp = yu + idx;
        *reinterpret_cast<float4*>(yp) =
            make_float4(a1[h][c][0], a2[h][c][0], a1[h][c][1], a2[h][c][1]);
        *reinterpret_cast<float4*>(yp + 2) =
            make_float4(a1[h][c][2], a2[h][c][2], a1[h][c][3], a2[h][c][3]);
        #pragma unroll
        for (int x = 0; x < 4; ++x) {
          float wgt = wy * wx[x];
          sc[c] += a1[h][c][x] * wgt;
          sq[c] += a1[h][c][x] * a1[h][c][x] * wgt;
        }
      }
    }
  }
  STATS_REDUCE_STORE(sc, sq, sums, bid)
}

// ---- LDS-tiled downsample conv (ratio<2.05): 32 x 8 tile, float2 out ----
template <int SMODE, bool IDENT>
__global__ __launch_bounds__(256) void conv_dn_t(
    const float* __restrict__ in, const float2* __restrict__ pyu,
    float2* __restrict__ yu,
    const float* __restrict__ w1, const float* __restrict__ b1,
    const float* __restrict__ w2, const float* __restrict__ b2,
    float* __restrict__ sums, int Hin, int S, int hc, int logr,
    int tilesX, int tilesY,
    const float* __restrict__ psums,
    const float* __restrict__ pinp, const float* __restrict__ plnp,
    const float* __restrict__ pbnp, const float* __restrict__ pbnw,
    const float* __restrict__ pbnb, const float* __restrict__ pp1,
    const float* __restrict__ pp2, const float* __restrict__ pnoise,
    int pN, int Sp, int logrp, int pNT, int pT) {
  const int TW = 32, TH = 8, IW = 68, IH = 20;
  __shared__ float lin[3 * IH * IW];
  __shared__ float pA[3], pB[3], pP2v, sred[12];
  int bid = xcd_swz();
  int tpi = tilesX * tilesY;
  int n = bid / tpi;
  int trem = bid - n * tpi;
  int tyB = trem / tilesX, txB = trem - tyB * tilesX;
  int px0 = txB * TW, py0 = tyB * TH;
  int sy0 = (py0 * hc) >> logr, sx0 = (px0 * hc) >> logr;
  const float* inb = in + (size_t)n * 3 * Hin * Hin;
  if (SMODE == 1) {
    compute_AB_P(psums, n, pNT, pT, (float)(Hin * Hin), (float)pN, pinp, plnp,
                 pbnp, pbnw, pbnb, pp1, pp2, pA, pB, &pP2v, sred);
    size_t pbase = (size_t)n * 3 * Sp * Sp;
    stage_tile<1, IDENT, IH>(lin, nullptr, 0, pyu, pbase, Hin, sy0, sx0, Sp,
                             logrp, pA, pB, pP2v, pnoise);
  } else if (SMODE == 2) {
    size_t ps = (size_t)96 * Hin * Hin;
    stage_tile<2, false, IH>(lin, inb, ps, nullptr, 0, Hin, sy0, sx0, 0, 0,
                             nullptr, nullptr, 0.f, nullptr);
  } else {
    stage_tile<0, false, IH>(lin, inb, 0, nullptr, 0, Hin, sy0, sx0, 0, 0,
                             nullptr, nullptr, 0.f, nullptr);
  }
  __syncthreads();
  int tx = threadIdx.x & 31, ty = threadIdx.x >> 5;
  int px = px0 + tx, py = py0 + ty;
  int sxl = ((px * hc) >> logr) - sx0;
  int syl = ((py * hc) >> logr) - sy0;
  float a1[3], a2[3];
  #pragma unroll
  for (int c = 0; c < 3; ++c) { a1[c] = b1[c]; a2[c] = b2[c]; }
  #pragma unroll
  for (int ci = 0; ci < 3; ++ci) {
    const float* lrow = lin + (ci * IH + syl) * IW + sxl;
    const float* wp1 = w1 + ci * 25;
    const float* wp2 = w2 + ci * 25;
    #pragma unroll
    for (int ky = 0; ky < 5; ++ky) {
      float v[5];
      #pragma unroll
      for (int j = 0; j < 5; ++j) { v[j] = lrow[ky * IW + j]; }
      #pragma unroll
      for (int c = 0; c < 3; ++c) {
        #pragma unroll
        for (int kx = 0; kx < 5; ++kx) {
          a1[c] = fmaf(v[kx], wp1[c * 75 + ky * 5 + kx], a1[c]);
          a2[c] = fmaf(v[kx], wp2[c * 75 + ky * 5 + kx], a2[c]);
        }
      }
    }
  }
  float sc[3] = {0.f, 0.f, 0.f}, sq[3] = {0.f, 0.f, 0.f};
  bool valid = (py < S) && (px < S);
  if (valid) {
    #pragma unroll
    for (int c = 0; c < 3; ++c) {
      size_t idx = ((size_t)(n * 3 + c) * S + py) * S + px;
      yu[idx] = make_float2(a1[c], a2[c]);
      sc[c] += a1[c];
      sq[c] += a1[c] * a1[c];
    }
  }
  STATS_REDUCE_STORE(sc, sq, sums, bid)
}

// ---- Linear 512->768: one wave per output row, coalesced float4 ----
__global__ __launch_bounds__(256) void linear_wave(
    const float* __restrict__ z, const float* __restrict__ w,
    const float* __restrict__ b, float* __restrict__ out) {
  int row = (blockIdx.x << 2) + (threadIdx.x >> 6);
  int lane = threadIdx.x & 63;
  const float4* wr = reinterpret_cast<const float4*>(w + (size_t)row * 512);
  const float4* zz = reinterpret_cast<const float4*>(z);
  float acc = 0.f;
  #pragma unroll
  for (int i = 0; i < 2; ++i) {
    float4 wv = wr[lane + 64 * i];
    float4 zv = zz[lane + 64 * i];
    acc += wv.x * zv.x + wv.y * zv.y + wv.z * zv.z + wv.w * zv.w;
  }
  #pragma unroll
  for (int off = 32; off; off >>= 1) acc += __shfl_down(acc, off);
  if (lane == 0) out[row] = acc + b[row];
}

// ---- noise conv path (blocks 0,1) in one block, L0 from global ----
__global__ __launch_bounds__(256) void noise_rest(
    const float* __restrict__ L0g,
    const float* __restrict__ cw, const float* __restrict__ cb,
    const float* __restrict__ c2w, const float* __restrict__ c2b,
    const float* __restrict__ inp, const float* __restrict__ lnp,
    const float* __restrict__ bnp, const float* __restrict__ bnw,
    const float* __restrict__ bnb, const float* __restrict__ p1p,
    const float* __restrict__ p2p, float* __restrict__ nb0) {
  __shared__ float L0[768];
  __shared__ float ys0[432], u20[432];
  __shared__ float buf1[3072];
  __shared__ float ys1[2352], u21[2352];
  __shared__ float redS[4][3], redQ[4][3];
  __shared__ float AB[6];
  int tid = threadIdx.x;
  for (int t = tid; t < 768; t += 256) { L0[t] = L0g[t]; }
  __syncthreads();
  // ---- conv0: (3,16,16) -> S=12, r=32 ----
  {
    float sc[3] = {0, 0, 0}, sq[3] = {0, 0, 0};
    for (int p = tid; p < 144; p += 256) {
      int py = p / 12, px = p - py * 12;
      float a1[3], a2[3];
      #pragma unroll
      for (int c = 0; c < 3; ++c) { a1[c] = cb[c]; a2[c] = c2b[c]; }
      for (int ci = 0; ci < 3; ++ci) {
        #pragma unroll
        for (int ky = 0; ky < 5; ++ky) {
          const float* row = &L0[ci * 256 + (py + ky) * 16 + px];
          #pragma unroll
          for (int c = 0; c < 3; ++c) {
            #pragma unroll
            for (int kx = 0; kx < 5; ++kx) {
              a1[c] = fmaf(row[kx], cw[c * 75 + ci * 25 + ky * 5 + kx], a1[c]);
              a2[c] = fmaf(row[kx], c2w[c * 75 + ci * 25 + ky * 5 + kx], a2[c]);
            }
          }
        }
      }
      int wy = ((py + 1) * 32 + 11) / 12 - (py * 32 + 11) / 12;
      int wx = ((px + 1) * 32 + 11) / 12 - (px * 32 + 11) / 12;
      float wgt = (float)(wy * wx);
      #pragma unroll
      for (int c = 0; c < 3; ++c) {
        ys0[c * 144 + p] = a1[c];
        u20[c * 144 + p] = a2[c];
        sc[c] += a1[c] * wgt;
        sq[c] += a1[c] * a1[c] * wgt;
      }
    }
    #pragma unroll
    for (int off = 32; off; off >>= 1) {
      #pragma unroll
      for (int c = 0; c < 3; ++c) {
        sc[c] += __shfl_down(sc[c], off);
        sq[c] += __shfl_down(sq[c], off);
      }
    }
    int wid = tid >> 6, lane = tid & 63;
    if (lane == 0) {
      #pragma unroll
      for (int c = 0; c < 3; ++c) { redS[wid][c] = sc[c]; redQ[wid][c] = sq[c]; }
    }
    __syncthreads();
    if (tid < 3) {
      int c = tid;
      float s1 = redS[0][c] + redS[1][c] + redS[2][c] + redS[3][c];
      float s2 = redQ[0][c] + redQ[1][c] + redQ[2][c] + redQ[3][c];
      float si_ = inp[0] + inp[1] + inp[2] + lnp[0] + lnp[1] + lnp[2];
      float sb = bnp[0] + bnp[1] + bnp[2];
      float2 ab = ab_from(s1, s2, s1, s2, 1024.f, 1.f, si_, sb, bnw[c], bnb[c], p1p[0]);
      AB[c] = ab.x; AB[3 + c] = ab.y;
    }
    __syncthreads();
  }
  {
    float P2a = p2p[0];
    for (int t = tid; t < 3072; t += 256) {
      int c = t >> 10, p = t & 1023;
      int oy = p >> 5, ox = p & 31;
      int si = ((oy * 12) >> 5) * 12 + ((ox * 12) >> 5);
      buf1[t] = AB[c] * ys0[c * 144 + si] + AB[3 + c] + P2a * u20[c * 144 + si];
    }
  }
  __syncthreads();
  // ---- conv1: (3,32,32) -> S=28, r=64 ----
  {
    const float* w1 = cw + 225;
    const float* w2 = c2w + 225;
    float sc[3] = {0, 0, 0}, sq[3] = {0, 0, 0};
    for (int p = tid; p < 784; p += 256) {
      int py = p / 28, px = p - py * 28;
      float a1[3], a2[3];
      #pragma unroll
      for (int c = 0; c < 3; ++c) { a1[c] = cb[3 + c]; a2[c] = c2b[3 + c]; }
      for (int ci = 0; ci < 3; ++ci) {
        #pragma unroll
        for (int ky = 0; ky < 5; ++ky) {
          const float* row = &buf1[ci * 1024 + (py + ky) * 32 + px];
          #pragma unroll
          for (int c = 0; c < 3; ++c) {
            #pragma unroll
            for (int kx = 0; kx < 5; ++kx) {
              a1[c] = fmaf(row[kx], w1[c * 75 + ci * 25 + ky * 5 + kx], a1[c]);
              a2[c] = fmaf(row[kx], w2[c * 75 + ci * 25 + ky * 5 + kx], a2[c]);
            }
          }
        }
      }
      int wy = ((py + 1) * 64 + 27) / 28 - (py * 64 + 27) / 28;
      int wx = ((px + 1) * 64 + 27) / 28 - (px * 64 + 27) / 28;
      float wgt = (float)(wy * wx);
      #pragma unroll
      for (int c = 0; c < 3; ++c) {
        ys1[c * 784 + p] = a1[c];
        u21[c * 784 + p] = a2[c];
        sc[c] += a1[c] * wgt;
        sq[c] += a1[c] * a1[c] * wgt;
      }
    }
    #pragma unroll
    for (int off = 32; off; off >>= 1) {
      #pragma unroll
      for (int c = 0; c < 3; ++c) {
        sc[c] += __shfl_down(sc[c], off);
        sq[c] += __shfl_down(sq[c], off);
      }
    }
    int wid = tid >> 6, lane = tid & 63;
    __syncthreads();  // protect redS reuse
    if (lane == 0) {
      #pragma unroll
      for (int c = 0; c < 3; ++c) { redS[wid][c] = sc[c]; redQ[wid][c] = sq[c]; }
    }
    __syncthreads();
    if (tid < 3) {
      int c = tid;
      float s1 = redS[0][c] + redS[1][c] + redS[2][c] + redS[3][c];
      float s2 = redQ[0][c] + redQ[1][c] + redQ[2][c] + redQ[3][c];
      float si_ = inp[3] + inp[4] + inp[5] + lnp[3] + lnp[4] + lnp[5];
      float sb = bnp[3] + bnp[4] + bnp[5];
      float2 ab = ab_from(s1, s2, s1, s2, 4096.f, 1.f, si_, sb, bnw[3 + c], bnb[3 + c], p1p[1]);
      AB[c] = ab.x; AB[3 + c] = ab.y;
    }
    __syncthreads();
  }
  {
    float P2b = p2p[1];
    for (int t = tid; t < 12288; t += 256) {
      int c = t >> 12, p = t & 4095;
      int oy = p >> 6, ox = p & 63;
      int si = ((oy * 28) >> 6) * 28 + ((ox * 28) >> 6);
      nb0[t] = AB[c] * ys1[c * 784 + si] + AB[3 + c] + P2b * u21[c * 784 + si];
    }
  }
}

// ---- attention HW=1024, pass 1 (fused y2+QKV recompute) ----
__global__ __launch_bounds__(256) void attn_rows_f(
    const float2* __restrict__ yu, const float* __restrict__ sums,
    const float* __restrict__ inp, const float* __restrict__ lnp,
    const float* __restrict__ bnp, const float* __restrict__ bnw,
    const float* __restrict__ bnb, const float* __restrict__ p1p,
    const float* __restrict__ p2p,
    const float* __restrict__ qw, const float* __restrict__ qb,
    const float* __restrict__ kw, const float* __restrict__ kb,
    float* __restrict__ Mp, float* __restrict__ Lp, int S,
    int pNT, int pT) {
  __shared__ float pA[3], pB[3], pP2v, sred[12];
  __shared__ __align__(16) float y2s[768], qs[768];
  int bid = blockIdx.x;
  int np = bid & 3; bid >>= 2;
  int mc = bid & 3;
  int b = bid >> 2;
  compute_AB_P(sums, b, pNT, pT, 1024.f, 32.f, inp, lnp, bnp, bnw, bnb, p1p,
               p2p, pA, pB, &pP2v, sred);
  size_t ybase = (size_t)b * 3 * S * S;
  for (int t = threadIdx.x; t < 768; t += 256) {
    int c = t >> 8, j = t & 255;
    int n = (np << 8) + j;
    int oy = n >> 5, ox = n & 31;
    int si = ((oy * S) >> 5) * S + ((ox * S) >> 5);
    float2 v = yu[ybase + c * S * S + si];
    y2s[t] = pA[c] * v.x + pB[c] + pP2v * v.y;
  }
  __syncthreads();
  for (int t = threadIdx.x; t < 768; t += 256) {
    int o = t >> 8, j = t & 255;
    qs[t] = qb[o] + qw[o * 3] * y2s[j] + qw[o * 3 + 1] * y2s[256 + j] +
            qw[o * 3 + 2] * y2s[512 + j];
  }
  __syncthreads();
  int m = (mc << 8) + threadIdx.x;
  int oy = m >> 5, ox = m & 31;
  int si = ((oy * S) >> 5) * S + ((ox * S) >> 5);
  float ym[3];
  #pragma unroll
  for (int c = 0; c < 3; ++c) {
    float2 v = yu[ybase + c * S * S + si];
    ym[c] = pA[c] * v.x + pB[c] + pP2v * v.y;
  }
  float k0 = (kb[0] + kw[0] * ym[0] + kw[1] * ym[1] + kw[2] * ym[2]) * LOG2E;
  float k1 = (kb[1] + kw[3] * ym[0] + kw[4] * ym[1] + kw[5] * ym[2]) * LOG2E;
  float k2 = (kb[2] + kw[6] * ym[0] + kw[7] * ym[1] + kw[8] * ym[2]) * LOG2E;
  const float4* qa4 = reinterpret_cast<const float4*>(qs);
  const float4* qb4 = reinterpret_cast<const float4*>(qs + 256);
  const float4* qc4 = reinterpret_cast<const float4*>(qs + 512);
  float mr = -1e30f;
  #pragma unroll 4
  for (int j = 0; j < 64; ++j) {
    float4 qa = qa4[j], qbv = qb4[j], qc = qc4[j];
    float s0 = k0 * qa.x + k1 * qbv.x + k2 * qc.x;
    float s1 = k0 * qa.y + k1 * qbv.y + k2 * qc.y;
    float s2 = k0 * qa.z + k1 * qbv.z + k2 * qc.z;
    float s3 = k0 * qa.w + k1 * qbv.w + k2 * qc.w;
    mr = fmaxf(mr, fmaxf(fmaxf(s0, s1), fmaxf(s2, s3)));
  }
  float l = 0.f;
  #pragma unroll 4
  for (int j = 0; j < 64; ++j) {
    float4 qa = qa4[j], qbv = qb4[j], qc = qc4[j];
    float s0 = k0 * qa.x + k1 * qbv.x + k2 * qc.x;
    float s1 = k0 * qa.y + k1 * qbv.y + k2 * qc.y;
    float s2 = k0 * qa.z + k1 * qbv.z + k2 * qc.z;
    float s3 = k0 * qa.w + k1 * qbv.w + k2 * qc.w;
    l += exp2f(s0 - mr) + exp2f(s1 - mr) + exp2f(s2 - mr) + exp2f(s3 - mr);
  }
  int idx = (b * 4 + np) * 1024 + m;
  Mp[idx] = mr;
  Lp[idx] = l;
}

// ---- attention HW=1024, pass 2: partial buffers, NO atomics ----
__global__ __launch_bounds__(256) void attn_out_f(
    const float2* __restrict__ yu, const float* __restrict__ sums,
    const float* __restrict__ inp, const float* __restrict__ lnp,
    const float* __restrict__ bnp, const float* __restrict__ bnw,
    const float* __restrict__ bnb, const float* __restrict__ p1p,
    const float* __restrict__ p2p,
    const float* __restrict__ qw, const float* __restrict__ qb,
    const float* __restrict__ kw, const float* __restrict__ kb,
    const float* __restrict__ vw, const float* __restrict__ vb,
    const float* __restrict__ Mp, const float* __restrict__ Lp,
    float* __restrict__ aout, int S, int pNT, int pT) {
  __shared__ float pA[3], pB[3], pP2v, sred[12];
  __shared__ __align__(16) float ym[768], ks[768], vs[768], Ms[256], Ls[256];
  int bid = blockIdx.x;
  int mp = bid & 3; bid >>= 2;
  int nc = bid & 3;
  int b = bid >> 2;
  compute_AB_P(sums, b, pNT, pT, 1024.f, 32.f, inp, lnp, bnp, bnw, bnb, p1p,
               p2p, pA, pB, &pP2v, sred);
  size_t ybase = (size_t)b * 3 * S * S;
  for (int t = threadIdx.x; t < 768; t += 256) {
    int c = t >> 8, j = t & 255;
    int m = (mp << 8) + j;
    int oy = m >> 5, ox = m & 31;
    int si = ((oy * S) >> 5) * S + ((ox * S) >> 5);
    float2 v = yu[ybase + c * S * S + si];
    ym[t] = pA[c] * v.x + pB[c] + pP2v * v.y;
  }
  __syncthreads();
  for (int t = threadIdx.x; t < 768; t += 256) {
    int o = t >> 8, j = t & 255;
    float y0 = ym[j], y1 = ym[256 + j], y2v = ym[512 + j];
    ks[t] = (kb[o] + kw[o * 3] * y0 + kw[o * 3 + 1] * y1 + kw[o * 3 + 2] * y2v) * LOG2E;
    vs[t] = vb[o] + vw[o * 3] * y0 + vw[o * 3 + 1] * y1 + vw[o * 3 + 2] * y2v;
  }
  {
    int t = threadIdx.x;
    int m = (mp << 8) + t;
    float M0 = Mp[(b * 4 + 0) * 1024 + m], M1 = Mp[(b * 4 + 1) * 1024 + m];
    float M2 = Mp[(b * 4 + 2) * 1024 + m], M3 = Mp[(b * 4 + 3) * 1024 + m];
    float L0 = Lp[(b * 4 + 0) * 1024 + m], L1 = Lp[(b * 4 + 1) * 1024 + m];
    float L2 = Lp[(b * 4 + 2) * 1024 + m], L3 = Lp[(b * 4 + 3) * 1024 + m];
    float MM = fmaxf(fmaxf(M0, M1), fmaxf(M2, M3));
    float LL = L0 * exp2f(M0 - MM) + L1 * exp2f(M1 - MM) +
               L2 * exp2f(M2 - MM) + L3 * exp2f(M3 - MM);
    Ms[t] = MM;
    Ls[t] = 1.0f / LL;
  }
  __syncthreads();
  int n = (nc << 8) + threadIdx.x;
  int oy = n >> 5, ox = n & 31;
  int si = ((oy * S) >> 5) * S + ((ox * S) >> 5);
  float yn[3];
  #pragma unroll
  for (int c = 0; c < 3; ++c) {
    float2 v = yu[ybase + c * S * S + si];
    yn[c] = pA[c] * v.x + pB[c] + pP2v * v.y;
  }
  float q0 = qb[0] + qw[0] * yn[0] + qw[1] * yn[1] + qw[2] * yn[2];
  float q1 = qb[1] + qw[3] * yn[0] + qw[4] * yn[1] + qw[5] * yn[2];
  float q2 = qb[2] + qw[6] * yn[0] + qw[7] * yn[1] + qw[8] * yn[2];
  float a0 = 0.f, a1 = 0.f, a2 = 0.f;
  const float4* ka4 = reinterpret_cast<const float4*>(ks);
  const float4* kb4 = reinterpret_cast<const float4*>(ks + 256);
  const float4* kc4 = reinterpret_cast<const float4*>(ks + 512);
  const float4* va4 = reinterpret_cast<const float4*>(vs);
  const float4* vb4 = reinterpret_cast<const float4*>(vs + 256);
  const float4* vc4 = reinterpret_cast<const float4*>(vs + 512);
  const float4* mm4 = reinterpret_cast<const float4*>(Ms);
  const float4* ll4 = reinterpret_cast<const float4*>(Ls);
  #pragma unroll 2
  for (int j = 0; j < 64; ++j) {
    float4 ka = ka4[j], kbv = kb4[j], kc = kc4[j];
    float4 va = va4[j], vbv = vb4[j], vc = vc4[j];
    float4 mm = mm4[j], ll = ll4[j];
    float s, w;
    s = ka.x * q0 + kbv.x * q1 + kc.x * q2;
    w = exp2f(s - mm.x) * ll.x;
    a0 = fmaf(va.x, w, a0); a1 = fmaf(vbv.x, w, a1); a2 = fmaf(vc.x, w, a2);
    s = ka.y * q0 + kbv.y * q1 + kc.y * q2;
    w = exp2f(s - mm.y) * ll.y;
    a0 = fmaf(va.y, w, a0); a1 = fmaf(vbv.y, w, a1); a2 = fmaf(vc.y, w, a2);
    s = ka.z * q0 + kbv.z * q1 + kc.z * q2;
    w = exp2f(s - mm.z) * ll.z;
    a0 = fmaf(va.z, w, a0); a1 = fmaf(vbv.z, w, a1); a2 = fmaf(vc.z, w, a2);
    s = ka.w * q0 + kbv.w * q1 + kc.w * q2;
    w = exp2f(s - mm.w) * ll.w;
    a0 = fmaf(va.w, w, a0); a1 = fmaf(vbv.w, w, a1); a2 = fmaf(vc.w, w, a2);
  }
  if (mp == 0) { a0 += yn[0]; a1 += yn[1]; a2 += yn[2]; }
  size_t o0 = (size_t)mp * 98304 + (size_t)b * 3072 + n;
  aout[o0] = a0;
  aout[o0 + 1024] = a1;
  aout[o0 + 2048] = a2;
}

// ---- attention HW=256 + following conv, 1024 threads, 4-way split loops ----
__global__ __launch_bounds__(1024) void attn256_conv(
    const float2* __restrict__ yu, const float* __restrict__ sums,
    const float* __restrict__ inp, const float* __restrict__ lnp,
    const float* __restrict__ bnp, const float* __restrict__ bnw,
    const float* __restrict__ bnb, const float* __restrict__ p1p,
    const float* __restrict__ p2p,
    const float* __restrict__ qw, const float* __restrict__ qb,
    const float* __restrict__ kw, const float* __restrict__ kb,
    const float* __restrict__ vw, const float* __restrict__ vb,
    const float* __restrict__ cw1, const float* __restrict__ cb1,
    const float* __restrict__ cw2, const float* __restrict__ cb2,
    float2* __restrict__ yu_out, float* __restrict__ sums_out, int S, int r,
    int pNT, int pT) {
  __shared__ float pA[3], pB[3], pP2v, sred[12];
  __shared__ __align__(16) float y2s[768], qs[768], ks[768], vs[768];
  __shared__ __align__(16) float Ms[256], Ls[256];
  __shared__ float Mq[1024], Lq[1024];
  __shared__ float Oq[3072];
  __shared__ float redS[16][3], redQ[16][3];
  int tid = threadIdx.x;
  int quarter = tid >> 8;
  int lane256 = tid & 255;
  int b = blockIdx.x;
  compute_AB_P(sums, b, pNT, pT, 256.f, 32.f, inp, lnp, bnp, bnw, bnb, p1p,
               p2p, pA, pB, &pP2v, sred);
  size_t ybase = (size_t)b * 3 * S * S;
  if (tid < 768) {
    int c = tid >> 8, p = tid & 255;
    int oy = p >> 4, ox = p & 15;
    int si = ((oy * S) >> 4) * S + ((ox * S) >> 4);
    float2 v = yu[ybase + c * S * S + si];
    y2s[tid] = pA[c] * v.x + pB[c] + pP2v * v.y;
  }
  __syncthreads();
  if (tid < 768) {
    int o = tid >> 8, p = tid & 255;
    float y0 = y2s[p], y1 = y2s[256 + p], y2v = y2s[512 + p];
    qs[tid] = qb[o] + qw[o * 3] * y0 + qw[o * 3 + 1] * y1 + qw[o * 3 + 2] * y2v;
    ks[tid] = (kb[o] + kw[o * 3] * y0 + kw[o * 3 + 1] * y1 + kw[o * 3 + 2] * y2v) * LOG2E;
    vs[tid] = vb[o] + vw[o * 3] * y0 + vw[o * 3 + 1] * y1 + vw[o * 3 + 2] * y2v;
  }
  __syncthreads();
  {
    int m = lane256;
    float kx = ks[m], ky = ks[256 + m], kz = ks[512 + m];
    int n0 = quarter << 6;
    const float4* qa4 = reinterpret_cast<const float4*>(qs + n0);
    const float4* qb4 = reinterpret_cast<const float4*>(qs + 256 + n0);
    const float4* qc4 = reinterpret_cast<const float4*>(qs + 512 + n0);
    float mr = -1e30f;
    #pragma unroll 4
    for (int j = 0; j < 16; ++j) {
      float4 qa = qa4[j], qbv = qb4[j], qc = qc4[j];
      float s0 = kx * qa.x + ky * qbv.x + kz * qc.x;
      float s1 = kx * qa.y + ky * qbv.y + kz * qc.y;
      float s2 = kx * qa.z + ky * qbv.z + kz * qc.z;
      float s3 = kx * qa.w + ky * qbv.w + kz * qc.w;
      mr = fmaxf(mr, fmaxf(fmaxf(s0, s1), fmaxf(s2, s3)));
    }
    float l = 0.f;
    #pragma unroll 4
    for (int j = 0; j < 16; ++j) {
      float4 qa = qa4[j], qbv = qb4[j], qc = qc4[j];
      float s0 = kx * qa.x + ky * qbv.x + kz * qc.x;
      float s1 = kx * qa.y + ky * qbv.y + kz * qc.y;
      float s2 = kx * qa.z + ky * qbv.z + kz * qc.z;
      float s3 = kx * qa.w + ky * qbv.w + kz * qc.w;
      l += exp2f(s0 - mr) + exp2f(s1 - mr) + exp2f(s2 - mr) + exp2f(s3 - mr);
    }
    Mq[tid] = mr;
    Lq[tid] = l;
  }
  __syncthreads();
  if (tid < 256) {
    float M0 = Mq[tid], M1 = Mq[256 + tid], M2 = Mq[512 + tid], M3 = Mq[768 + tid];
    float L0 = Lq[tid], L1 = Lq[256 + tid], L2 = Lq[512 + tid], L3 = Lq[768 + tid];
    float MM = fmaxf(fmaxf(M0, M1), fmaxf(M2, M3));
    float LL = L0 * exp2f(M0 - MM) + L1 * exp2f(M1 - MM) +
               L2 * exp2f(M2 - MM) + L3 * exp2f(M3 - MM);
    Ms[tid] = MM;
    Ls[tid] = 1.0f / LL;
  }
  __syncthreads();
  {
    int n = lane256;
    float q0 = qs[n], q1 = qs[256 + n], q2 = qs[512 + n];
    int m0 = quarter << 6;
    const float4* ka4 = reinterpret_cast<const float4*>(ks + m0);
    const float4* kb4 = reinterpret_cast<const float4*>(ks + 256 + m0);
    const float4* kc4 = reinterpret_cast<const float4*>(ks + 512 + m0);
    const float4* va4 = reinterpret_cast<const float4*>(vs + m0);
    const float4* vb4 = reinterpret_cast<const float4*>(vs + 256 + m0);
    const float4* vc4 = reinterpret_cast<const float4*>(vs + 512 + m0);
    const float4* mm4 = reinterpret_cast<const float4*>(Ms + m0);
    const float4* ll4 = reinterpret_cast<const float4*>(Ls + m0);
    float a0 = 0.f, a1 = 0.f, a2 = 0.f;
    #pragma unroll 4
    for (int j = 0; j < 16; ++j) {
      float4 ka = ka4[j], kbv = kb4[j], kc = kc4[j];
      float4 va = va4[j], vbv = vb4[j], vc = vc4[j];
      float4 mm = mm4[j], ll = ll4[j];
      float s, w;
      s = ka.x * q0 + kbv.x * q1 + kc.x * q2;
      w = exp2f(s - mm.x) * ll.x;
      a0 = fmaf(va.x, w, a0); a1 = fmaf(vbv.x, w, a1); a2 = fmaf(vc.x, w, a2);
      s = ka.y * q0 + kbv.y * q1 + kc.y * q2;
      w = exp2f(s - mm.y) * ll.y;
      a0 = fmaf(va.y, w, a0); a1 = fmaf(vbv.y, w, a1); a2 = fmaf(vc.y, w, a2);
      s = ka.z * q0 + kbv.z * q1 + kc.z * q2;
      w = exp2f(s - mm.z) * ll.z;
      a0 = fmaf(va.z, w, a0); a1 = fmaf(vbv.z, w, a1); a2 = fmaf(vc.z, w, a2);
      s = ka.w * q0 + kbv.w * q1 + kc.w * q2;
      w = exp2f(s - mm.w) * ll.w;
      a0 = fmaf(va.w, w, a0); a1 = fmaf(vbv.w, w, a1); a2 = fmaf(vc.w, w, a2);
    }
    Oq[tid] = a0;
    Oq[1024 + tid] = a1;
    Oq[2048 + tid] = a2;
  }
  __syncthreads();
  if (tid < 768) {
    int c = tid >> 8, n = tid & 255;
    int cb_ = c << 10;
    y2s[tid] += Oq[cb_ + n] + Oq[cb_ + 256 + n] + Oq[cb_ + 512 + n] + Oq[cb_ + 768 + n];
  }
  __syncthreads();
  float sc[3] = {0.f, 0.f, 0.f}, sq[3] = {0.f, 0.f, 0.f};
  int p = tid;
  if (p < 144) {
    int py = p / 12, px = p - py * 12;
    float a1[3], a2[3];
    #pragma unroll
    for (int c = 0; c < 3; ++c) { a1[c] = cb1[c]; a2[c] = cb2[c]; }
    #pragma unroll
    for (int ci = 0; ci < 3; ++ci) {
      #pragma unroll
      for (int ky = 0; ky < 5; ++ky) {
        const float* row = &y2s[ci * 256 + (py + ky) * 16 + px];
        #pragma unroll
        for (int c = 0; c < 3; ++c) {
          #pragma unroll
          for (int kx = 0; kx < 5; ++kx) {
            a1[c] = fmaf(row[kx], cw1[c * 75 + ci * 25 + ky * 5 + kx], a1[c]);
            a2[c] = fmaf(row[kx], cw2[c * 75 + ci * 25 + ky * 5 + kx], a2[c]);
          }
        }
      }
    }
    float wy = (float)(((py + 1) * r + 11) / 12 - (py * r + 11) / 12);
    float wx = (float)(((px + 1) * r + 11) / 12 - (px * r + 11) / 12);
    float wgt = wy * wx;
    #pragma unroll
    for (int c = 0; c < 3; ++c) {
      yu_out[(size_t)(b * 3 + c) * 144 + p] = make_float2(a1[c], a2[c]);
      sc[c] += a1[c] * wgt;
      sq[c] += a1[c] * a1[c] * wgt;
    }
  }
  #pragma unroll
  for (int off = 32; off; off >>= 1) {
    #pragma unroll
    for (int c = 0; c < 3; ++c) {
      sc[c] += __shfl_down(sc[c], off);
      sq[c] += __shfl_down(sq[c], off);
    }
  }
  int wid = tid >> 6, lane = tid & 63;
  if (lane == 0) {
    #pragma unroll
    for (int c = 0; c < 3; ++c) { redS[wid][c] = sc[c]; redQ[wid][c] = sq[c]; }
  }
  __syncthreads();
  if (tid < 3) {
    int c = tid;
    float s1 = 0.f, s2 = 0.f;
    #pragma unroll
    for (int w = 0; w < 16; ++w) { s1 += redS[w][c]; s2 += redQ[w][c]; }
    int NTg = (int)gridDim.x;  // 32, one block per image -> plain store
    sums_out[(2 * c) * NTg + b] = s1;
    sums_out[(2 * c + 1) * NTg + b] = s2;
  }
}

// ---- rank-144 attention (+conv) on a SRC=12 grid upsampled to UP; quad-split.
// UP=32: attn8+conv9 (verified R11 instance). UP=16: attn7+conv8.
template <int UP, int CO, int R>
__global__ __launch_bounds__(1024) void attn144up_k(
    const float2* __restrict__ yin, const float* __restrict__ sums,
    const float* __restrict__ inp, const float* __restrict__ lnp,
    const float* __restrict__ bnp, const float* __restrict__ bnw,
    const float* __restrict__ bnb, const float* __restrict__ p1p,
    const float* __restrict__ p2p,
    const float* __restrict__ qw, const float* __restrict__ qb,
    const float* __restrict__ kw, const float* __restrict__ kb,
    const float* __restrict__ vw, const float* __restrict__ vb,
    const float* __restrict__ cw1, const float* __restrict__ cb1,
    const float* __restrict__ cw2, const float* __restrict__ cb2,
    float2* __restrict__ yu_out, float* __restrict__ sums_out) {
  const int SRC = 12;
  __shared__ float pA[3], pB[3], pP2v, sred[12];
  __shared__ float y2[432], Osh[432];
  __shared__ __align__(16) float4 qkp[144];  // (q0,q1,q2, wn)
  __shared__ __align__(16) float4 ksp[144];  // (k*log2e x3, M_row)
  __shared__ __align__(16) float4 vsp[144];  // (v0,v1,v2, wn/l)
  __shared__ float redS16[16][3], redQ16[16][3];
  int b = blockIdx.x;
  int t = threadIdx.x;
  compute_AB_P(sums, b, 32, 1, (float)(UP * UP), 32.f, inp, lnp, bnp, bnw,
               bnb, p1p, p2p, pA, pB, &pP2v, sred);
  if (t < 432) {
    int c = t / 144, j = t - c * 144;
    float2 v = yin[(size_t)(b * 3 + c) * 144 + j];
    y2[t] = pA[c] * v.x + pB[c] + pP2v * v.y;
  }
  __syncthreads();
  if (t < 144) {
    int j = t;
    float y0 = y2[j], y1 = y2[144 + j], y2v = y2[288 + j];
    int jy = j / 12, jx = j - jy * 12;
    int cy = (UP * (jy + 1) + SRC - 1) / SRC - (UP * jy + SRC - 1) / SRC;
    int cx = (UP * (jx + 1) + SRC - 1) / SRC - (UP * jx + SRC - 1) / SRC;
    float wnv = (float)(cy * cx);
    qkp[j] = make_float4(
        qb[0] + qw[0] * y0 + qw[1] * y1 + qw[2] * y2v,
        qb[1] + qw[3] * y0 + qw[4] * y1 + qw[5] * y2v,
        qb[2] + qw[6] * y0 + qw[7] * y1 + qw[8] * y2v, wnv);
    ksp[j] = make_float4(
        (kb[0] + kw[0] * y0 + kw[1] * y1 + kw[2] * y2v) * LOG2E,
        (kb[1] + kw[3] * y0 + kw[4] * y1 + kw[5] * y2v) * LOG2E,
        (kb[2] + kw[6] * y0 + kw[7] * y1 + kw[8] * y2v) * LOG2E, 0.f);
    vsp[j] = make_float4(
        vb[0] + vw[0] * y0 + vw[1] * y1 + vw[2] * y2v,
        vb[1] + vw[3] * y0 + vw[4] * y1 + vw[5] * y2v,
        vb[2] + vw[6] * y0 + vw[7] * y1 + vw[8] * y2v, 0.f);
  }
  __syncthreads();
  int m4 = t >> 2, part = t & 3;
  // M/L: quad (4 lanes) per row m4; each part reduces 36 of 144 terms.
  if (m4 < 144) {
    float4 kk = ksp[m4];
    int n0 = part * 36;
    float mr = -1e30f;
    #pragma unroll 4
    for (int nn = n0; nn < n0 + 36; ++nn) {
      float4 q4 = qkp[nn];
      float s = kk.x * q4.x + kk.y * q4.y + kk.z * q4.z;
      mr = fmaxf(mr, s);
    }
    mr = fmaxf(mr, __shfl_xor(mr, 1));
    mr = fmaxf(mr, __shfl_xor(mr, 2));
    float l = 0.f;
    #pragma unroll 4
    for (int nn = n0; nn < n0 + 36; ++nn) {
      float4 q4 = qkp[nn];
      float s = kk.x * q4.x + kk.y * q4.y + kk.z * q4.z;
      l += q4.w * exp2f(s - mr);
    }
    l += __shfl_xor(l, 1);
    l += __shfl_xor(l, 2);
    if (part == 0) {
      ksp[m4].w = mr;
      vsp[m4].w = qkp[m4].w / l;  // wn[m] / l[m]
    }
  }
  __syncthreads();
  // PV: quad per query row; each part sums 36 of 144 keys.
  if (m4 < 144) {
    int nq = m4;
    float4 q4 = qkp[nq];
    int m0 = part * 36;
    float a0 = 0.f, a1 = 0.f, a2 = 0.f;
    #pragma unroll 4
    for (int m = m0; m < m0 + 36; ++m) {
      float4 k4 = ksp[m];
      float4 v4 = vsp[m];
      float s = k4.x * q4.x + k4.y * q4.y + k4.z * q4.z;
      float w = exp2f(s - k4.w) * v4.w;
      a0 = fmaf(v4.x, w, a0);
      a1 = fmaf(v4.y, w, a1);
      a2 = fmaf(v4.z, w, a2);
    }
    a0 += __shfl_xor(a0, 1);
    a0 += __shfl_xor(a0, 2);
    a1 += __shfl_xor(a1, 1);
    a1 += __shfl_xor(a1, 2);
    a2 += __shfl_xor(a2, 1);
    a2 += __shfl_xor(a2, 2);
    if (part == 0) {
      Osh[nq] = a0 + y2[nq];
      Osh[144 + nq] = a1 + y2[144 + nq];
      Osh[288 + nq] = a2 + y2[288 + nq];
    }
  }
  __syncthreads();
  // conv: SRC-grid upsampled to UP, 5x5 valid -> CO x CO, upsample factor R
  float sc[3] = {0.f, 0.f, 0.f}, sq[3] = {0.f, 0.f, 0.f};
  if (t < CO * CO) {
    int py = t / CO, px = t - py * CO;
    float a1[3], a2[3];
    #pragma unroll
    for (int c = 0; c < 3; ++c) { a1[c] = cb1[c]; a2[c] = cb2[c]; }
    #pragma unroll
    for (int ci = 0; ci < 3; ++ci) {
      const float* obase = &Osh[ci * 144];
      #pragma unroll
      for (int ky = 0; ky < 5; ++ky) {
        int sy = ((py + ky) * SRC) / UP;
        const float* orow = obase + sy * 12;
        #pragma unroll
        for (int kx = 0; kx < 5; ++kx) {
          int sx = ((px + kx) * SRC) / UP;
          float v = orow[sx];
          #pragma unroll
          for (int c = 0; c < 3; ++c) {
            a1[c] = fmaf(v, cw1[c * 75 + ci * 25 + ky * 5 + kx], a1[c]);
            a2[c] = fmaf(v, cw2[c * 75 + ci * 25 + ky * 5 + kx], a2[c]);
          }
        }
      }
    }
    float wy = (float)(((py + 1) * R + CO - 1) / CO - (py * R + CO - 1) / CO);
    float wx = (float)(((px + 1) * R + CO - 1) / CO - (px * R + CO - 1) / CO);
    float wgt = wy * wx;
    #pragma unroll
    for (int c = 0; c < 3; ++c) {
      yu_out[((size_t)(b * 3 + c) * CO + py) * CO + px] = make_float2(a1[c], a2[c]);
      sc[c] += a1[c] * wgt;
      sq[c] += a1[c] * a1[c] * wgt;
    }
  }
  // 16-wave stats reduce, plain store
  #pragma unroll
  for (int off = 32; off; off >>= 1) {
    #pragma unroll
    for (int c = 0; c < 3; ++c) {
      sc[c] += __shfl_down(sc[c], off);
      sq[c] += __shfl_down(sq[c], off);
    }
  }
  int wid = t >> 6, lane = t & 63;
  if (lane == 0) {
    #pragma unroll
    for (int c = 0; c < 3; ++c) { redS16[wid][c] = sc[c]; redQ16[wid][c] = sq[c]; }
  }
  __syncthreads();
  if (t < 3) {
    int c = t;
    float s1 = 0.f, s2 = 0.f;
    #pragma unroll
    for (int w = 0; w < 16; ++w) { s1 += redS16[w][c]; s2 += redQ16[w][c]; }
    sums_out[(2 * c) * 32 + b] = s1;
    sums_out[(2 * c + 1) * 32 + b] = s2;
  }
}

// ---- final: affine + p2*u2 + tanh -> out; 2048 blocks, float4 stores ----
__global__ __launch_bounds__(256) void elem_final(
    const float2* __restrict__ yu, const float* __restrict__ sums,
    const float* __restrict__ inp, const float* __restrict__ lnp,
    const float* __restrict__ bnp, const float* __restrict__ bnw,
    const float* __restrict__ bnb, const float* __restrict__ p1p,
    const float* __restrict__ p2p, float* __restrict__ out, int S,
    int pNT, int pT) {
  __shared__ float pA[3], pB[3], pP2v, sred[12];
  int bid = xcd_swz();
  int n = bid >> 6;
  int part = bid & 63;
  compute_AB_P(sums, n, pNT, pT, 65536.f, 32.f, inp, lnp, bnp, bnw, bnb, p1p,
               p2p, pA, pB, &pP2v, sred);
  int p0 = (part << 10) + ((int)threadIdx.x << 2);
  int oy = p0 >> 8;
  int oxb = p0 & 255;
  int sy = ((oy * S) >> 8) * S;
  int si0 = sy + ((oxb * S) >> 8);
  int si1 = sy + (((oxb + 1) * S) >> 8);
  int si2 = sy + (((oxb + 2) * S) >> 8);
  int si3 = sy + (((oxb + 3) * S) >> 8);
  size_t ybase = (size_t)n * 3 * S * S;
  #pragma unroll
  for (int c = 0; c < 3; ++c) {
    const float2* yp = yu + ybase + (size_t)c * S * S;
    float2 v0 = yp[si0], v1 = yp[si1], v2 = yp[si2], v3 = yp[si3];
    float4 r;
    r.x = tanhf(pA[c] * v0.x + pB[c] + pP2v * v0.y);
    r.y = tanhf(pA[c] * v1.x + pB[c] + pP2v * v1.y);
    r.z = tanhf(pA[c] * v2.x + pB[c] + pP2v * v2.y);
    r.w = tanhf(pA[c] * v3.x + pB[c] + pP2v * v3.y);
    *reinterpret_cast<float4*>(&out[((size_t)(n * 3 + c) << 16) + p0]) = r;
  }
}

#define NPX nullptr, nullptr, nullptr, nullptr, nullptr, nullptr, nullptr, \
            nullptr, nullptr, 0, 0, 0, 0, 0

extern "C" void kernel_launch(void* const* d_in, const int* in_sizes, int n_in,
                              void* d_out, int out_size, void* d_ws, size_t ws_size,
                              hipStream_t stream) {
  const float* x       = (const float*)d_in[0];
  const float* noise_z = (const float*)d_in[1];
  const float* lin_w   = (const float*)d_in[2];
  const float* lin_b   = (const float*)d_in[3];
  const float* conv_w  = (const float*)d_in[4];
  const float* conv_b  = (const float*)d_in[5];
  const float* conv2_w = (const float*)d_in[6];
  const float* conv2_b = (const float*)d_in[7];
  const float* q_w     = (const float*)d_in[8];
  const float* q_b     = (const float*)d_in[9];
  const float* k_w     = (const float*)d_in[10];
  const float* k_b     = (const float*)d_in[11];
  const float* v_w     = (const float*)d_in[12];
  const float* v_b     = (const float*)d_in[13];
  const float* in_p    = (const float*)d_in[14];
  const float* ln_p    = (const float*)d_in[15];
  const float* bn_p    = (const float*)d_in[16];
  const float* bn_w    = (const float*)d_in[17];
  const float* bn_b    = (const float*)d_in[18];
  const float* p1      = (const float*)d_in[19];
  const float* p2      = (const float*)d_in[20];
  float* out = (float*)d_out;

  float* ws = (float*)d_ws;
  size_t off = 0;
  auto alloc = [&](size_t nf) { float* p = ws + off; off += nf; return p; };
  // per-stage partial stats, planar [6][NT]; NT = producer grid size
  float* PS    = alloc(27264);
  float* PS2   = PS;            // conv2:  NT=1024
  float* PS3   = PS + 6144;     // conv3:  NT=2048
  float* PS4   = PS + 18432;    // conv4:  NT=512
  float* PS5   = PS + 21504;    // conv5:  NT=128
  float* PS6   = PS + 22272;    // conv6:  NT=64
  float* PS6a  = PS + 22656;    // attn6:  NT=32
  float* PS7a  = PS + 22848;    // attn7:  NT=32
  float* PS9   = PS + 23040;    // attn144c9: NT=32
  float* PS10  = PS + 23424;    // conv10: NT=128
  float* PS11  = PS + 24192;    // conv11: NT=512
  float* P45  = alloc(393216);
  float2* YU2 = (float2*)alloc(12192768);
  float2* PA  = (float2*)alloc(3145728);
  float2* PB  = (float2*)alloc(3145728);
  float* Mp   = alloc(131072);
  float* Lp   = alloc(131072);
  float* NB0  = alloc(12288);
  float* LIN  = alloc(768);

  const float* nul = nullptr;
  const float2* nul2 = nullptr;

  linear_wave<<<192, 256, 0, stream>>>(noise_z, lin_w, lin_b, LIN);
  noise_rest<<<1, 256, 0, stream>>>(LIN, conv_w, conv_b, conv2_w, conv2_b,
      in_p, ln_p, bn_p, bn_w, bn_b, p1, p2, NB0);

  // conv2: x -> YU2 (S=252, r=256), 64x32 tile, async global->LDS staging
  conv_up_t<0, 32><<<1024, 256, 0, stream>>>(x, nul2, YU2, conv_w + 450,
      conv_b + 6, conv2_w + 450, conv2_b + 6, PS2, 256, 252, 256, 4, 8,
      NPX);
  // conv3: fused(b2) YU2 -> PA (S=128), 32x8 tile; prev Sp=252, logrp=8
  conv_dn_t<1, false><<<2048, 256, 0, stream>>>(nul, YU2, PA,
      conv_w + 675, conv_b + 9, conv2_w + 675, conv2_b + 9, PS3,
      256, 128, 252, 7, 4, 16,
      PS2, in_p + 6, ln_p + 6, bn_p + 6, bn_w + 6, bn_b + 6, p1 + 2,
      p2 + 2, nul, 32, 252, 8, 1024, 32);
  // conv4: fused(b3) PA -> PB (S=64); prev identity
  conv_dn_t<1, true><<<512, 256, 0, stream>>>(nul, PA, PB,
      conv_w + 900, conv_b + 12, conv2_w + 900, conv2_b + 12, PS4,
      128, 64, 124, 6, 2, 8,
      PS3, in_p + 9, ln_p + 9, bn_p + 9, bn_w + 9, bn_b + 9, p1 + 3,
      p2 + 3, nul, 32, 128, 7, 2048, 64);
  // conv5: fused(b4)+noise PB -> PA (S=32); prev identity
  conv_dn_t<1, true><<<128, 256, 0, stream>>>(nul, PB, PA,
      conv_w + 1125, conv_b + 15, conv2_w + 1125, conv2_b + 15, PS5,
      64, 32, 60, 5, 1, 4,
      PS4, in_p + 12, ln_p + 12, bn_p + 12, bn_w + 12, bn_b + 12, p1 + 4,
      p2 + 4, NB0, 32, 64, 6, 512, 16);
  // attn5 (HW=1024) on PA (S=32) -> partials P45
  attn_rows_f<<<512, 256, 0, stream>>>(PA, PS5, in_p + 15, ln_p + 15,
      bn_p + 15, bn_w + 15, bn_b + 15, p1 + 5, p2 + 5,
      q_w + 45, q_b + 15, k_w + 45, k_b + 15, Mp, Lp, 32, 128, 4);
  attn_out_f<<<512, 256, 0, stream>>>(PA, PS5, in_p + 15, ln_p + 15,
      bn_p + 15, bn_w + 15, bn_b + 15, p1 + 5, p2 + 5,
      q_w + 45, q_b + 15, k_w + 45, k_b + 15, v_w + 45, v_b + 15, Mp, Lp, P45,
      32, 128, 4);
  // conv6: SUM4 staging from P45 -> PB (S=16)
  conv_dn_t<2, false><<<64, 256, 0, stream>>>(P45, nul2, PB,
      conv_w + 1350, conv_b + 18, conv2_w + 1350, conv2_b + 18, PS6,
      32, 16, 28, 4, 1, 2, NPX);
  // attn6 (HW=256, full-rank) on PB (S=16) + conv7 (r=16) -> PA (144)
  attn256_conv<<<32, 1024, 0, stream>>>(PB, PS6, in_p + 18, ln_p + 18,
      bn_p + 18, bn_w + 18, bn_b + 18, p1 + 6, p2 + 6,
      q_w + 54, q_b + 18, k_w + 54, k_b + 18, v_w + 54, v_b + 18,
      conv_w + 1575, conv_b + 21, conv2_w + 1575, conv2_b + 21,
      PA, PS6a, 16, 16, 64, 2);
  // attn7 (rank-144, 12->16 multiplicity) + conv8 (16-grid -> 12, r=32) -> PB
  attn144up_k<16, 12, 32><<<32, 1024, 0, stream>>>(PA, PS6a, in_p + 21,
      ln_p + 21, bn_p + 21, bn_w + 21, bn_b + 21, p1 + 7, p2 + 7,
      q_w + 63, q_b + 21, k_w + 63, k_b + 21, v_w + 63, v_b + 21,
      conv_w + 1800, conv_b + 24, conv2_w + 1800, conv2_b + 24,
      PB, PS7a);
  // attn8 (rank-144, 12->32 multiplicity) + conv9 (32-grid -> 28, r=64) -> PA
  attn144up_k<32, 28, 64><<<32, 1024, 0, stream>>>(PB, PS7a, in_p + 24,
      ln_p + 24, bn_p + 24, bn_w + 24, bn_b + 24, p1 + 8, p2 + 8,
      q_w + 72, q_b + 24, k_w + 72, k_b + 24, v_w + 72, v_b + 24,
      conv_w + 2025, conv_b + 27, conv2_w + 2025, conv2_b + 27,
      PA, PS9);
  // conv10: fused(b9) PA -> PB (S=60); prev Sp=28, logrp=6; stats NT=32,T=1
  conv_up_t<1, 16><<<128, 256, 0, stream>>>(nul, PA, PB, conv_w + 2250,
      conv_b + 30, conv2_w + 2250, conv2_b + 30, PS10, 64, 60, 128, 1, 4,
      PS9, in_p + 27, ln_p + 27, bn_p + 27, bn_w + 27, bn_b + 27,
      p1 + 9, p2 + 9, nul, 32, 28, 6, 32, 1);
  // conv11: fused(b10) PB -> YU2 (S=124); prev Sp=60, logrp=7
  conv_up_t<1, 16><<<512, 256, 0, stream>>>(nul, PB, YU2, conv_w + 2475,
      conv_b + 33, conv2_w + 2475, conv2_b + 33, PS11, 128, 124, 256, 2, 8,
      PS10, in_p + 30, ln_p + 30, bn_p + 30, bn_w + 30, bn_b + 30,
      p1 + 10, p2 + 10, nul, 32, 60, 7, 128, 4);
  // final: tanh -> out (2048 blocks, 4 px/thread, float4 stores)
  elem_final<<<2048, 256, 0, stream>>>(YU2, PS11, in_p + 33, ln_p + 33,
      bn_p + 33, bn_w + 33, bn_b + 33, p1 + 11, p2 + 11, out, 124, 512, 16);
}